// Round 7
// baseline (1587.512 us; speedup 1.0000x reference)
//
#include <hip/hip_runtime.h>
#include <math.h>

// ---------------------------------------------------------------------------
// SAGPool GNN forward: 3x [GCNConv -> SAGPool(top-k) -> readout] + MLP head.
// B=32 graphs x N=2048 nodes; E=524288; 128 feats; K = 1024/512/256.
// R19 changes vs R16 (296us best; R18's 64-row mm0 REVERTED: 2-wave blocks
// latency-bound, 60us):
//   - mm/csr byte-identical to R16 (512-thr, 128x128, BK=32 dbuf).
//   - agg+pool fused per layer (k_aggpool): pool blocks (bid<32) spin on
//     per-graph agg counters; agg blocks release after threadfence+barrier.
//     R14's version of this died from __launch_bounds__(1024,8) -> VGPR=32
//     -> spills (VALU 1.3%). Now __launch_bounds__(1024) (VGPR cap 128).
//     Dispatches 9 -> 6; pool overlaps agg tail per-graph.
// ---------------------------------------------------------------------------

namespace {

constexpr int B_  = 32;
constexpr int N_  = 2048;
constexpr int NT  = B_ * N_;        // 65536
constexpr int EPG = 16384;
constexpr int E_  = B_ * EPG;       // 524288
constexpr int NCLS = 10;
constexpr int AST = 132;            // A-tile LDS row stride (128 + 4 pad)

// logical block id -> tile, grouping graphs g%8 per XCD (id%8=XCD).
__device__ __forceinline__ int relabel(int bid, int bpgsh) {
  int x = bid & 7, slot = bid >> 3;
  int g = x + 8 * (slot >> bpgsh);
  return (g << bpgsh) + (slot & ((1 << bpgsh) - 1));
}

// ---- CSR build + layer-0 norm, 512-thread variant (runs inside mm0 grid) --
// One block per graph. hist = 2048 bins + 8 scan cells, aliased LDS.
__device__ void csr_build(const int* __restrict__ src, const int* __restrict__ dst,
                          int* __restrict__ off, int* __restrict__ srcp,
                          float* __restrict__ dinv, float* __restrict__ ds,
                          float* __restrict__ sws, int* hist, int* __restrict__ cnt) {
  const int g = blockIdx.x;    // blocks 0..31, %8 = XCD = g%8
  const int t = threadIdx.x;   // 0..511
  const int base_n = g * N_;
  const int base_e = g * EPG;
  int* wsum8 = hist + 2048;
  if (g == 0 && t < 96) cnt[t] = 0;   // zero layer sync counters each launch
#pragma unroll
  for (int i = 0; i < 4; ++i) hist[t + 512 * i] = 0;
  __syncthreads();
  // phase 1: in-degree histogram (LDS atomics), 8-deep batched loads
  for (int i = 0; i < EPG / 512; i += 8) {
    int dd[8];
#pragma unroll
    for (int j = 0; j < 8; ++j) dd[j] = dst[base_e + t + 512 * (i + j)];
#pragma unroll
    for (int j = 0; j < 8; ++j) atomicAdd(&hist[dd[j] - base_n], 1);
  }
  __syncthreads();
  // phase 2: exclusive scan over 2048 bins, 4 bins/thread
  int a[4], ssum = 0;
#pragma unroll
  for (int i = 0; i < 4; ++i) { a[i] = hist[4 * t + i]; ssum += a[i]; }
  {
    int lane = t & 63, w = t >> 6;   // 8 waves
    int v = ssum;
#pragma unroll
    for (int o = 1; o < 64; o <<= 1) {
      int nv = __shfl_up(v, o);
      if (lane >= o) v += nv;
    }
    if (lane == 63) wsum8[w] = v;
    __syncthreads();
    if (t == 0) {
      int accv = 0;
      for (int i = 0; i < 8; ++i) { int tmp = wsum8[i]; wsum8[i] = accv; accv += tmp; }
    }
    __syncthreads();
    int run = wsum8[w] + v - ssum;
#pragma unroll
    for (int i = 0; i < 4; ++i) {
      int n = 4 * t + i;
      off[base_n + n] = base_e + run;
      hist[n] = run;                 // LDS cursor (own bins only: safe)
      float d0 = 1.f + (float)a[i];  // deg = 1 + indegree (layer-0 masks = 1)
      float di0 = 1.f / sqrtf(d0);
      dinv[base_n + n] = di0;
      ds[base_n + n] = di0;
      sws[base_n + n] = di0 * di0;
      run += a[i];
    }
    if (g == B_ - 1 && t == 0) off[NT] = E_;
  }
  __syncthreads();
  // phase 3: place srcp in CSR slot order via LDS cursors
  for (int i = 0; i < EPG / 512; i += 8) {
    int dd[8], ss[8];
#pragma unroll
    for (int j = 0; j < 8; ++j) {
      int e = base_e + t + 512 * (i + j);
      dd[j] = dst[e];
      ss[j] = src[e];
    }
#pragma unroll
    for (int j = 0; j < 8; ++j) {
      int slot = atomicAdd(&hist[dd[j] - base_n], 1);
      srcp[base_e + slot] = ss[j];
    }
  }
}

// ---- dense matmul + fused readout of its input rows (R16) ------------------
// C[rows x 128] = A[rows x 128] @ W. 128x128 tile / 512 thr; 4x8 per thread;
// BK=32 LDS dbuf (67.6KB). Blocks [0,csrBlocks) run csr_build (layer 0).
__global__ __launch_bounds__(512) void k_matmul(const float* __restrict__ A,
                                                const float* __restrict__ W,
                                                float* __restrict__ C,
                                                const int* __restrict__ kept,
                                                int kshift, int bpgsh,
                                                const float* __restrict__ scaleArr,
                                                float* __restrict__ pmx,
                                                float* __restrict__ psm,
                                                const int* __restrict__ src,
                                                const int* __restrict__ dst,
                                                int* __restrict__ off,
                                                int* __restrict__ srcp,
                                                float* __restrict__ dinvW,
                                                float* __restrict__ dsW,
                                                float* __restrict__ swsW,
                                                int* __restrict__ cnt,
                                                int csrBlocks) {
  __shared__ float Ast[2][32 * AST];   // 33.8 KB
  __shared__ float Ws[2][32 * 128];    // 32.8 KB
  __shared__ int rowid[128];
  __shared__ float rsc[128];
  if ((int)blockIdx.x < csrBlocks) {
    csr_build(src, dst, off, srcp, dinvW, dsW, swsW, (int*)&Ast[0][0], cnt);
    return;
  }
  const int tid = threadIdx.x;   // 0..511
  const int tile = relabel((int)blockIdx.x - csrBlocks, bpgsh);
  if (kept) {
    if (tid < 128) {
      int q = tile * 128 + tid;
      int g = q >> kshift;
      int row = kept[g * N_ + (q - (g << kshift))];
      rowid[tid] = row;
      rsc[tid] = scaleArr[row];
    }
    __syncthreads();
  }
  const int rowq = tid >> 4;   // 0..31: rows 4*rowq..+3
  const int colq = tid & 15;   // cols {4c..4c+3, 64+4c..+3}
  float4 va[2], vw[2];
#pragma unroll
  for (int i = 0; i < 2; ++i) {
    int idx = tid + 512 * i;
    int row = idx >> 3, f4 = idx & 7;
    int grw = kept ? rowid[row] : tile * 128 + row;
    va[i] = *(const float4*)&A[(size_t)grw * 128 + 4 * f4];
  }
#pragma unroll
  for (int i = 0; i < 2; ++i) {
    int idx = tid + 512 * i;
    int kk = idx >> 5, cf = idx & 31;
    vw[i] = *(const float4*)&W[(size_t)kk * 128 + 4 * cf];
  }
#pragma unroll
  for (int i = 0; i < 2; ++i) {
    int idx = tid + 512 * i;
    int row = idx >> 3, f4 = idx & 7;
    Ast[0][(4 * f4 + 0) * AST + row] = va[i].x;
    Ast[0][(4 * f4 + 1) * AST + row] = va[i].y;
    Ast[0][(4 * f4 + 2) * AST + row] = va[i].z;
    Ast[0][(4 * f4 + 3) * AST + row] = va[i].w;
  }
#pragma unroll
  for (int i = 0; i < 2; ++i) {
    int idx = tid + 512 * i;
    int kk = idx >> 5, cf = idx & 31;
    *(float4*)&Ws[0][kk * 128 + 4 * cf] = vw[i];
  }
  __syncthreads();
  float acc[4][8] = {};
  for (int c = 0; c < 4; ++c) {
    int cur = c & 1;
    if (c < 3) {
      int k0n = 32 * (c + 1);
#pragma unroll
      for (int i = 0; i < 2; ++i) {
        int idx = tid + 512 * i;
        int row = idx >> 3, f4 = idx & 7;
        int grw = kept ? rowid[row] : tile * 128 + row;
        va[i] = *(const float4*)&A[(size_t)grw * 128 + k0n + 4 * f4];
      }
#pragma unroll
      for (int i = 0; i < 2; ++i) {
        int idx = tid + 512 * i;
        int kk = idx >> 5, cf = idx & 31;
        vw[i] = *(const float4*)&W[(size_t)(k0n + kk) * 128 + 4 * cf];
      }
    }
#pragma unroll 2
    for (int kk = 0; kk < 32; ++kk) {
      float4 a0 = *(const float4*)&Ast[cur][kk * AST + 4 * rowq];
      float4 w0 = *(const float4*)&Ws[cur][kk * 128 + 4 * colq];
      float4 w1 = *(const float4*)&Ws[cur][kk * 128 + 64 + 4 * colq];
      float a[4] = {a0.x, a0.y, a0.z, a0.w};
      float w[8] = {w0.x, w0.y, w0.z, w0.w, w1.x, w1.y, w1.z, w1.w};
#pragma unroll
      for (int r = 0; r < 4; ++r)
#pragma unroll
        for (int cc = 0; cc < 8; ++cc) acc[r][cc] += a[r] * w[cc];
    }
    // fused readout of this chunk's 32 feats from the staged tile
    if (kept) {
      int kkf = tid >> 4;            // feat within chunk, 0..31
      int r0 = (tid & 15) * 8;       // 8-row slice per thread
      float mxv = -INFINITY, smv = 0.f;
#pragma unroll
      for (int rr = 0; rr < 8; rr += 4) {
        float4 av = *(const float4*)&Ast[cur][kkf * AST + r0 + rr];
        float4 s4 = *(const float4*)&rsc[r0 + rr];
        float v0 = av.x * s4.x, v1 = av.y * s4.y;
        float v2 = av.z * s4.z, v3 = av.w * s4.w;
        mxv = fmaxf(fmaxf(fmaxf(mxv, v0), fmaxf(v1, v2)), v3);
        smv += v0 + v1 + v2 + v3;
      }
#pragma unroll
      for (int o = 8; o >= 1; o >>= 1) {
        mxv = fmaxf(mxv, __shfl_down(mxv, o, 16));
        smv += __shfl_down(smv, o, 16);
      }
      if ((tid & 15) == 0) {
        pmx[(size_t)tile * 128 + 32 * c + kkf] = mxv;
        psm[(size_t)tile * 128 + 32 * c + kkf] = smv;
      }
    }
    if (c < 3) {
      int nxt = cur ^ 1;
#pragma unroll
      for (int i = 0; i < 2; ++i) {
        int idx = tid + 512 * i;
        int row = idx >> 3, f4 = idx & 7;
        Ast[nxt][(4 * f4 + 0) * AST + row] = va[i].x;
        Ast[nxt][(4 * f4 + 1) * AST + row] = va[i].y;
        Ast[nxt][(4 * f4 + 2) * AST + row] = va[i].z;
        Ast[nxt][(4 * f4 + 3) * AST + row] = va[i].w;
      }
#pragma unroll
      for (int i = 0; i < 2; ++i) {
        int idx = tid + 512 * i;
        int kk = idx >> 5, cf = idx & 31;
        *(float4*)&Ws[nxt][kk * 128 + 4 * cf] = vw[i];
      }
      __syncthreads();
    }
  }
#pragma unroll
  for (int r = 0; r < 4; ++r) {
    int grw = kept ? rowid[4 * rowq + r] : tile * 128 + 4 * rowq + r;
    float* Crow = &C[(size_t)grw * 128];
    *(float4*)&Crow[4 * colq] = make_float4(acc[r][0], acc[r][1], acc[r][2], acc[r][3]);
    *(float4*)&Crow[64 + 4 * colq] = make_float4(acc[r][4], acc[r][5], acc[r][6], acc[r][7]);
  }
}

// ---- pool body (1024 thr): top-k select + masks + (layer-2 readout + head) -
__device__ void pool_body(const float* __restrict__ t1,
                          const int* __restrict__ off,
                          const int* __restrict__ srcp,
                          float* __restrict__ dinv,
                          float* __restrict__ ds,
                          float* __restrict__ sws,
                          float* __restrict__ scale,
                          const float* __restrict__ bp,
                          int* __restrict__ kept,
                          const float4* __restrict__ h4,
                          float invk, int k,
                          const int* __restrict__ inKept, int klen, int g,
                          const float* __restrict__ pmxA,
                          const float* __restrict__ psmA,
                          const float* __restrict__ pmxB,
                          const float* __restrict__ psmB,
                          const float* __restrict__ hW1,
                          const float* __restrict__ hb1,
                          const float* __restrict__ hW2,
                          const float* __restrict__ hb2,
                          const float* __restrict__ hW3,
                          const float* __restrict__ hb3,
                          float* __restrict__ out) {
  __shared__ float st1[2048];       // t1 in; scale after selection
  __shared__ float sdv[2048];
  __shared__ float skp[2048];
  __shared__ int skept[1024];
  __shared__ unsigned rephist[4096];  // 16 waves x 256 bins; reused as red[]
  __shared__ unsigned ebits[64];
  __shared__ int wsum[16];
  __shared__ unsigned bc_digit, bc_prev;
  __shared__ float gr[256], o1[128], o2[64], o3[NCLS];
  const int t = threadIdx.x;
  const int base = g * N_;
  st1[t] = t1[base + t];
  st1[t + 1024] = t1[base + t + 1024];
  sdv[t] = dinv[base + t];
  sdv[t + 1024] = dinv[base + t + 1024];
  skp[t] = 0.f;
  skp[t + 1024] = 0.f;
  if (t < 64) ebits[t] = 0u;
#pragma unroll
  for (int i = 0; i < 4; ++i) rephist[t + 1024 * i] = 0u;
  __syncthreads();
  int nodeq[2] = {-1, -1};
  float raw[2] = {0.f, 0.f};
  unsigned key[2] = {0xFFFFFFFFu, 0xFFFFFFFFu};
  float bpv = bp[0];
#pragma unroll
  for (int q = 0; q < 2; ++q) {
    int i = t + q * 1024;
    if (i >= klen) continue;
    int n = inKept ? (inKept[base + i] - base) : i;
    nodeq[q] = n;
    float di = sdv[n];
    float a = 0.f;
    int s = off[base + n], en = off[base + n + 1];
    int j = s;
    for (; j + 8 <= en; j += 8) {
      int sv[8];
#pragma unroll
      for (int i2 = 0; i2 < 8; ++i2) sv[i2] = srcp[j + i2] - base;
#pragma unroll
      for (int i2 = 0; i2 < 8; ++i2) a += sdv[sv[i2]] * st1[sv[i2]];
    }
    for (; j < en; ++j) {
      int sl = srcp[j] - base;
      a += sdv[sl] * st1[sl];
    }
    raw[q] = di * di * st1[n] + di * a + bpv;
    unsigned u = __float_as_uint(raw[q]);
    u = (u & 0x80000000u) ? ~u : (u | 0x80000000u);
    u = ~u;  // descending
    if (di <= 0.f) u = 0xFFFFFFFFu;
    key[q] = u;
  }
  // radix-select k-th largest score
  unsigned prefix = 0u, rem = (unsigned)k;
  const int wv = t >> 6;
  for (int shift = 24; shift >= 0; shift -= 8) {
    unsigned mask = (shift == 24) ? 0u : (0xFFFFFFFFu << (shift + 8));
#pragma unroll
    for (int q = 0; q < 2; ++q)
      if (nodeq[q] >= 0 && (key[q] & mask) == prefix)
        atomicAdd(&rephist[(wv << 8) + ((key[q] >> shift) & 255u)], 1u);
    __syncthreads();
    unsigned binv = 0u, v = 0u;
    if (t < 256) {
#pragma unroll
      for (int w = 0; w < 16; ++w) binv += rephist[(w << 8) + t];
      v = binv;
#pragma unroll
      for (int o = 1; o < 64; o <<= 1) {
        unsigned nv = __shfl_up(v, o);
        if ((t & 63) >= o) v += nv;
      }
      if ((t & 63) == 63) wsum[t >> 6] = (int)v;
    }
    __syncthreads();
    if (t < 256) {
      unsigned pre = 0u;
      int w4 = t >> 6;
      for (int u = 0; u < w4; ++u) pre += (unsigned)wsum[u];
      unsigned inc = v + pre, exc = inc - binv;
      if (inc >= rem && exc < rem) { bc_digit = (unsigned)t; bc_prev = exc; }
    }
    __syncthreads();
    if (shift > 0) {
#pragma unroll
      for (int i = 0; i < 4; ++i) rephist[t + 1024 * i] = 0u;
    }
    __syncthreads();
    prefix |= bc_digit << shift;
    rem -= bc_prev;
  }
  const unsigned Tkey = prefix;
  const int need = (int)rem;  // ties, lowest index first
#pragma unroll
  for (int q = 0; q < 2; ++q) {
    int n = nodeq[q];
    if (n >= 0 && key[q] == Tkey) atomicOr(&ebits[n >> 5], 1u << (n & 31));
  }
  __syncthreads();
#pragma unroll
  for (int q = 0; q < 2; ++q) {
    int n = nodeq[q];
    if (n < 0) continue;
    float kp;
    if (key[q] < Tkey) {
      kp = 1.f;
    } else if (key[q] == Tkey) {
      int w = n >> 5;
      int rank = __popc(ebits[w] & ((1u << (n & 31)) - 1u));
      for (int u = 0; u < w; ++u) rank += __popc(ebits[u]);
      kp = (rank < need) ? 1.f : 0.f;
    } else {
      kp = 0.f;
    }
    skp[n] = kp;
    float sc = kp * tanhf(raw[q]);
    st1[n] = sc;
    scale[base + n] = sc;
  }
  __syncthreads();
  // compacted kept list -> global + LDS
  {
    int lane = t & 63, w = t >> 6;
    int a0 = (int)skp[2 * t], a1 = (int)skp[2 * t + 1];
    int ps = a0 + a1;
    int v = ps;
#pragma unroll
    for (int o = 1; o < 64; o <<= 1) {
      int nv = __shfl_up(v, o);
      if (lane >= o) v += nv;
    }
    if (lane == 63) wsum[w] = v;
    __syncthreads();
    if (t == 0) {
      int accv = 0;
      for (int i = 0; i < 16; ++i) { int tmp = wsum[i]; wsum[i] = accv; accv += tmp; }
    }
    __syncthreads();
    int excl = wsum[w] + v - ps;
    if (a0) { kept[base + excl] = base + 2 * t; skept[excl] = base + 2 * t; }
    if (a1) { kept[base + excl + a0] = base + 2 * t + 1; skept[excl + a0] = base + 2 * t + 1; }
  }
  // next-layer dinv/ds/sws from new nmask (surviving nodes only)
#pragma unroll
  for (int q = 0; q < 2; ++q) {
    int n = nodeq[q];
    if (n < 0) continue;
    float nm = skp[n];
    float d = nm;
    int s = off[base + n], en = off[base + n + 1];
    int j = s;
    for (; j + 8 <= en; j += 8) {
      int sv[8];
#pragma unroll
      for (int i2 = 0; i2 < 8; ++i2) sv[i2] = srcp[j + i2] - base;
#pragma unroll
      for (int i2 = 0; i2 < 8; ++i2) d += skp[sv[i2]];
    }
    for (; j < en; ++j) d += skp[srcp[j] - base];
    float di = (nm > 0.f) ? (1.f / sqrtf(d)) : 0.f;
    float sc = st1[n];
    dinv[base + n] = di;
    ds[base + n] = di * sc;
    sws[base + n] = di * di * sc;
  }
  if (!out) return;
  __syncthreads();
  // layer-3 readout over kept list
  const int lane = t & 31, ng = t >> 5;
  float4 mx = make_float4(-INFINITY, -INFINITY, -INFINITY, -INFINITY);
  float4 sm = make_float4(0.f, 0.f, 0.f, 0.f);
  for (int i = ng; i < k; i += 32) {
    int node = skept[i];
    float sc = st1[node - base];
    float4 v = h4[(size_t)node * 32 + lane];
    v.x *= sc; v.y *= sc; v.z *= sc; v.w *= sc;
    mx.x = fmaxf(mx.x, v.x); mx.y = fmaxf(mx.y, v.y);
    mx.z = fmaxf(mx.z, v.z); mx.w = fmaxf(mx.w, v.w);
    sm.x += v.x; sm.y += v.y; sm.z += v.z; sm.w += v.w;
  }
  float4* red = (float4*)rephist;
  for (int d = 16; d >= 1; d >>= 1) {
    if (ng >= d && ng < 2 * d) {
      red[(ng - d) * 32 + lane] = mx;
      red[512 + (ng - d) * 32 + lane] = sm;
    }
    __syncthreads();
    if (ng < d) {
      float4 omx = red[ng * 32 + lane];
      float4 osm = red[512 + ng * 32 + lane];
      mx.x = fmaxf(mx.x, omx.x); mx.y = fmaxf(mx.y, omx.y);
      mx.z = fmaxf(mx.z, omx.z); mx.w = fmaxf(mx.w, omx.w);
      sm.x += osm.x; sm.y += osm.y; sm.z += osm.z; sm.w += osm.w;
    }
    __syncthreads();
  }
  if (ng == 0) {
    gr[4 * lane + 0] = mx.x;
    gr[4 * lane + 1] = mx.y;
    gr[4 * lane + 2] = mx.z;
    gr[4 * lane + 3] = mx.w;
    gr[128 + 4 * lane + 0] = sm.x * invk;
    gr[128 + 4 * lane + 1] = sm.y * invk;
    gr[128 + 4 * lane + 2] = sm.z * invk;
    gr[128 + 4 * lane + 3] = sm.w * invk;
  }
  __syncthreads();
  // fused MLP head + log_softmax
  if (t < 128) {
    float mxA = -INFINITY, smA = 0.f;
#pragma unroll
    for (int p = 0; p < 8; ++p) {
      mxA = fmaxf(mxA, pmxA[(size_t)(g * 8 + p) * 128 + t]);
      smA += psmA[(size_t)(g * 8 + p) * 128 + t];
    }
    float mxB = -INFINITY, smB = 0.f;
#pragma unroll
    for (int p = 0; p < 4; ++p) {
      mxB = fmaxf(mxB, pmxB[(size_t)(g * 4 + p) * 128 + t]);
      smB += psmB[(size_t)(g * 4 + p) * 128 + t];
    }
    gr[t] += mxA + mxB;
    gr[t + 128] += smA * (1.f / 1024.f) + smB * (1.f / 512.f);
  }
  __syncthreads();
  if (t < 128) {
    float a = hb1[t];
    for (int kk = 0; kk < 256; ++kk) a += gr[kk] * hW1[kk * 128 + t];
    o1[t] = fmaxf(a, 0.f);
  }
  __syncthreads();
  if (t < 64) {
    float a2 = hb2[t];
    for (int kk = 0; kk < 128; ++kk) a2 += o1[kk] * hW2[kk * 64 + t];
    o2[t] = fmaxf(a2, 0.f);
  }
  __syncthreads();
  if (t < NCLS) {
    float a3 = hb3[t];
    for (int kk = 0; kk < 64; ++kk) a3 += o2[kk] * hW3[kk * NCLS + t];
    o3[t] = a3;
  }
  __syncthreads();
  if (t == 0) {
    float m = -INFINITY;
    for (int c = 0; c < NCLS; ++c) m = fmaxf(m, o3[c]);
    float sum = 0.f;
    for (int c = 0; c < NCLS; ++c) sum += expf(o3[c] - m);
    float lse = logf(sum);
    for (int c = 0; c < NCLS; ++c) out[g * NCLS + c] = o3[c] - m - lse;
  }
}

// ---- fused agg (bid>=32) + pool (bid<32, spins on per-graph counters) ------
// NO min-waves bound: VGPR cap 128 (R14's ,8 forced 32 -> spills).
__global__ __launch_bounds__(1024) void k_aggpool(
    const float4* __restrict__ t4, const int* __restrict__ off,
    const int* __restrict__ srcp, float* __restrict__ dinv,
    float* __restrict__ ds, float* __restrict__ sws,
    const float* __restrict__ bias, const float* __restrict__ Wp,
    float4* __restrict__ h4, float* __restrict__ t1,
    const int* __restrict__ inKept, int kshift, int aggBpgsh, int aggPerG,
    int* __restrict__ cnt,
    float* __restrict__ scale, const float* __restrict__ bp,
    int* __restrict__ kept, float invk, int k, int klen,
    const float* __restrict__ pmxA, const float* __restrict__ psmA,
    const float* __restrict__ pmxB, const float* __restrict__ psmB,
    const float* __restrict__ hW1, const float* __restrict__ hb1,
    const float* __restrict__ hW2, const float* __restrict__ hb2,
    const float* __restrict__ hW3, const float* __restrict__ hb3,
    float* __restrict__ out) {
  const int tid = threadIdx.x;
  if ((int)blockIdx.x < 32) {
    // ---- pool role: wait for this graph's agg blocks, then select+mask ----
    const int g = ((int)blockIdx.x & 7) + 8 * ((int)blockIdx.x >> 3);
    if (tid == 0) {
      while (__hip_atomic_load(&cnt[g], __ATOMIC_ACQUIRE,
                               __HIP_MEMORY_SCOPE_AGENT) < aggPerG)
        __builtin_amdgcn_s_sleep(32);
    }
    __syncthreads();
    pool_body(t1, off, srcp, dinv, ds, sws, scale, bp, kept, h4, invk, k,
              inKept, klen, g, pmxA, psmA, pmxB, psmB,
              hW1, hb1, hW2, hb2, hW3, hb3, out);
    return;
  }
  // ---- agg role: 32 nodes/block, 32 lanes/node (same per-node code as R16) -
  int q = relabel((int)blockIdx.x - 32, aggBpgsh) * 32 + (tid >> 5);
  int node;
  if (inKept) {
    int g = q >> kshift;
    node = inKept[g * N_ + (q - (g << kshift))];
  } else {
    node = q;
  }
  const int lane = tid & 31;
  const float dvi = dinv[node];
  float sw = sws[node];
  float4 self = t4[(size_t)node * 32 + lane];
  float4 acc = make_float4(sw * self.x, sw * self.y, sw * self.z, sw * self.w);
  int s = off[node], en = off[node + 1];
  int j = s;
  for (; j + 8 <= en; j += 8) {
    int sv[8];
    float cv[8];
#pragma unroll
    for (int i = 0; i < 8; ++i) sv[i] = srcp[j + i];
#pragma unroll
    for (int i = 0; i < 8; ++i) cv[i] = ds[sv[i]] * dvi;
#pragma unroll
    for (int i = 0; i < 8; ++i) {
      if (cv[i] != 0.f) {
        float4 r = t4[(size_t)sv[i] * 32 + lane];
        acc.x += cv[i] * r.x; acc.y += cv[i] * r.y;
        acc.z += cv[i] * r.z; acc.w += cv[i] * r.w;
      }
    }
  }
  for (; j < en; ++j) {
    int s0 = srcp[j];
    float c0 = ds[s0] * dvi;
    if (c0 != 0.f) {
      float4 r0 = t4[(size_t)s0 * 32 + lane];
      acc.x += c0 * r0.x; acc.y += c0 * r0.y; acc.z += c0 * r0.z; acc.w += c0 * r0.w;
    }
  }
  float4 b4 = ((const float4*)bias)[lane];
  acc.x = fmaxf(acc.x + b4.x, 0.f);
  acc.y = fmaxf(acc.y + b4.y, 0.f);
  acc.z = fmaxf(acc.z + b4.z, 0.f);
  acc.w = fmaxf(acc.w + b4.w, 0.f);
  h4[(size_t)node * 32 + lane] = acc;
  float4 wp = ((const float4*)Wp)[lane];
  float part = acc.x * wp.x + acc.y * wp.y + acc.z * wp.z + acc.w * wp.w;
#pragma unroll
  for (int o = 16; o > 0; o >>= 1) part += __shfl_down(part, o, 32);
  if (lane == 0) t1[node] = part;
  // release: all threads' stores drained, then barrier, then one atomic
  __threadfence();
  __syncthreads();
  if (tid == 0) atomicAdd(&cnt[q >> kshift], 1);
}

}  // namespace

extern "C" void kernel_launch(void* const* d_in, const int* in_sizes, int n_in,
                              void* d_out, int out_size, void* d_ws, size_t ws_size,
                              hipStream_t stream) {
  const float* x = (const float*)d_in[0];
  const int* ei = (const int*)d_in[1];
  const int* src = ei;
  const int* dst = ei + E_;
  const float* Wl[3]  = {(const float*)d_in[3], (const float*)d_in[7], (const float*)d_in[11]};
  const float* bl[3]  = {(const float*)d_in[4], (const float*)d_in[8], (const float*)d_in[12]};
  const float* Wpl[3] = {(const float*)d_in[5], (const float*)d_in[9], (const float*)d_in[13]};
  const float* bpl[3] = {(const float*)d_in[6], (const float*)d_in[10], (const float*)d_in[14]};
  const float* l1W = (const float*)d_in[15];
  const float* l1b = (const float*)d_in[16];
  const float* l2W = (const float*)d_in[17];
  const float* l2b = (const float*)d_in[18];
  const float* l3W = (const float*)d_in[19];
  const float* l3b = (const float*)d_in[20];

  char* p = (char*)d_ws;
  auto alloc = [&](size_t bytes) -> void* {
    void* r = (void*)p;
    p += (bytes + 255) & ~size_t(255);
    return r;
  };
  float* h      = (float*)alloc((size_t)NT * 128 * 4);
  float* t      = (float*)alloc((size_t)NT * 128 * 4);
  float* dinv   = (float*)alloc(NT * 4);
  float* ds     = (float*)alloc(NT * 4);
  float* sws    = (float*)alloc(NT * 4);
  float* scale  = (float*)alloc(NT * 4);
  float* t1     = (float*)alloc(NT * 4);
  int*   srcp   = (int*)alloc(E_ * 4);
  int*   off    = (int*)alloc((NT + 1) * 4);
  int*   kept0  = (int*)alloc(NT * 4);
  int*   kept1  = (int*)alloc(NT * 4);
  int*   kept2  = (int*)alloc(NT * 4);
  float* pmxA   = (float*)alloc(256 * 128 * 4);
  float* psmA   = (float*)alloc(256 * 128 * 4);
  float* pmxB   = (float*)alloc(128 * 128 * 4);
  float* psmB   = (float*)alloc(128 * 128 * 4);
  int*   cnt    = (int*)alloc(96 * 4);          // 3 layers x 32 graph counters

  int* keptL[3] = {kept0, kept1, kept2};
  const int K[3] = {1024, 512, 256};
  const int KSH[3] = {10, 9, 8};
  float* pmxL[3] = {nullptr, pmxA, pmxB};
  float* psmL[3] = {nullptr, psmA, psmB};

  const float* inF = x;
  for (int l = 0; l < 3; ++l) {
    const int* inKept = (l == 0) ? nullptr : keptL[l - 1];
    int inKsh = (l == 0) ? 11 : KSH[l - 1];
    int nrows = (l == 0) ? NT : B_ * K[l - 1];
    int mm_bpgsh = (l == 0) ? 4 : (l == 1 ? 3 : 2);   // 512/256/128 mm blocks
    int csrB = (l == 0) ? B_ : 0;                     // csr piggybacks on mm0
    int aggB = nrows / 32;                            // 2048/1024/512 blocks
    int aggPerG = (nrows / B_) / 32;                  // 64/32/16 per graph
    int aggBpgsh = (l == 0) ? 6 : (l == 1 ? 5 : 4);
    int klen = (l == 0) ? N_ : K[l - 1];
    bool last = (l == 2);
    k_matmul<<<nrows / 128 + csrB, 512, 0, stream>>>(
        inF, Wl[l], t, inKept, inKsh, mm_bpgsh, scale, pmxL[l], psmL[l],
        src, dst, off, srcp, dinv, ds, sws, cnt, csrB);
    k_aggpool<<<32 + aggB, 1024, 0, stream>>>(
        (const float4*)t, off, srcp, dinv, ds, sws, bl[l], Wpl[l],
        (float4*)h, t1, inKept, inKsh, aggBpgsh, aggPerG, cnt + 32 * l,
        scale, bpl[l], keptL[l], 1.f / (float)K[l], K[l], klen,
        last ? pmxA : nullptr, last ? psmA : nullptr,
        last ? pmxB : nullptr, last ? psmB : nullptr,
        l1W, l1b, l2W, l2b, l3W, l3b, last ? (float*)d_out : nullptr);
    inF = h;
  }
}

// Round 8
// 301.619 us; speedup vs baseline: 5.2633x; 5.2633x over previous
//
#include <hip/hip_runtime.h>
#include <math.h>

// ---------------------------------------------------------------------------
// SAGPool GNN forward: 3x [GCNConv -> SAGPool(top-k) -> readout] + MLP head.
// B=32 graphs x N=2048 nodes; E=524288; 128 feats; K = 1024/512/256.
// R20 changes vs R16 (296us best; R14/R19 spin-fusion ABANDONED: agent-scope
// __threadfence => per-wave L2 writeback storm on non-coherent XCD L2s,
// ~800us at 1.3% VALU):
//   - pool's two edge-loop phases extracted to full-grid gather kernels:
//     k_score (raw score aggregation, 8 lanes/node, before pool) and
//     k_norm (next-layer dinv/ds/sws from kpmask, 8 lanes/node, after pool).
//     Pool itself: load raw -> radix select -> compact -> mask writes ->
//     (last layer) readout+head. Pool ran on 32 blocks (12.5% of CUs); the
//     extracted phases now run device-wide.
//   - mm (incl. csr piggyback + fused readout), agg, head: identical to R16.
// ---------------------------------------------------------------------------

namespace {

constexpr int B_  = 32;
constexpr int N_  = 2048;
constexpr int NT  = B_ * N_;        // 65536
constexpr int EPG = 16384;
constexpr int E_  = B_ * EPG;       // 524288
constexpr int NCLS = 10;
constexpr int AST = 132;            // A-tile LDS row stride (128 + 4 pad)

// logical block id -> tile, grouping graphs g%8 per XCD (id%8=XCD).
__device__ __forceinline__ int relabel(int bid, int bpgsh) {
  int x = bid & 7, slot = bid >> 3;
  int g = x + 8 * (slot >> bpgsh);
  return (g << bpgsh) + (slot & ((1 << bpgsh) - 1));
}

// ---- CSR build + layer-0 norm, 512-thread variant (runs inside mm0 grid) --
__device__ void csr_build(const int* __restrict__ src, const int* __restrict__ dst,
                          int* __restrict__ off, int* __restrict__ srcp,
                          float* __restrict__ dinv, float* __restrict__ ds,
                          float* __restrict__ sws, int* hist) {
  const int g = blockIdx.x;    // blocks 0..31, %8 = XCD = g%8
  const int t = threadIdx.x;   // 0..511
  const int base_n = g * N_;
  const int base_e = g * EPG;
  int* wsum8 = hist + 2048;
#pragma unroll
  for (int i = 0; i < 4; ++i) hist[t + 512 * i] = 0;
  __syncthreads();
  for (int i = 0; i < EPG / 512; i += 8) {
    int dd[8];
#pragma unroll
    for (int j = 0; j < 8; ++j) dd[j] = dst[base_e + t + 512 * (i + j)];
#pragma unroll
    for (int j = 0; j < 8; ++j) atomicAdd(&hist[dd[j] - base_n], 1);
  }
  __syncthreads();
  int a[4], ssum = 0;
#pragma unroll
  for (int i = 0; i < 4; ++i) { a[i] = hist[4 * t + i]; ssum += a[i]; }
  {
    int lane = t & 63, w = t >> 6;   // 8 waves
    int v = ssum;
#pragma unroll
    for (int o = 1; o < 64; o <<= 1) {
      int nv = __shfl_up(v, o);
      if (lane >= o) v += nv;
    }
    if (lane == 63) wsum8[w] = v;
    __syncthreads();
    if (t == 0) {
      int accv = 0;
      for (int i = 0; i < 8; ++i) { int tmp = wsum8[i]; wsum8[i] = accv; accv += tmp; }
    }
    __syncthreads();
    int run = wsum8[w] + v - ssum;
#pragma unroll
    for (int i = 0; i < 4; ++i) {
      int n = 4 * t + i;
      off[base_n + n] = base_e + run;
      hist[n] = run;                 // LDS cursor (own bins only: safe)
      float d0 = 1.f + (float)a[i];  // deg = 1 + indegree (layer-0 masks = 1)
      float di0 = 1.f / sqrtf(d0);
      dinv[base_n + n] = di0;
      ds[base_n + n] = di0;
      sws[base_n + n] = di0 * di0;
      run += a[i];
    }
    if (g == B_ - 1 && t == 0) off[NT] = E_;
  }
  __syncthreads();
  for (int i = 0; i < EPG / 512; i += 8) {
    int dd[8], ss[8];
#pragma unroll
    for (int j = 0; j < 8; ++j) {
      int e = base_e + t + 512 * (i + j);
      dd[j] = dst[e];
      ss[j] = src[e];
    }
#pragma unroll
    for (int j = 0; j < 8; ++j) {
      int slot = atomicAdd(&hist[dd[j] - base_n], 1);
      srcp[base_e + slot] = ss[j];
    }
  }
}

// ---- dense matmul + fused readout of its input rows (R16) ------------------
__global__ __launch_bounds__(512) void k_matmul(const float* __restrict__ A,
                                                const float* __restrict__ W,
                                                float* __restrict__ C,
                                                const int* __restrict__ kept,
                                                int kshift, int bpgsh,
                                                const float* __restrict__ scaleArr,
                                                float* __restrict__ pmx,
                                                float* __restrict__ psm,
                                                const int* __restrict__ src,
                                                const int* __restrict__ dst,
                                                int* __restrict__ off,
                                                int* __restrict__ srcp,
                                                float* __restrict__ dinvW,
                                                float* __restrict__ dsW,
                                                float* __restrict__ swsW,
                                                int csrBlocks) {
  __shared__ float Ast[2][32 * AST];   // 33.8 KB
  __shared__ float Ws[2][32 * 128];    // 32.8 KB
  __shared__ int rowid[128];
  __shared__ float rsc[128];
  if ((int)blockIdx.x < csrBlocks) {
    csr_build(src, dst, off, srcp, dinvW, dsW, swsW, (int*)&Ast[0][0]);
    return;
  }
  const int tid = threadIdx.x;   // 0..511
  const int tile = relabel((int)blockIdx.x - csrBlocks, bpgsh);
  if (kept) {
    if (tid < 128) {
      int q = tile * 128 + tid;
      int g = q >> kshift;
      int row = kept[g * N_ + (q - (g << kshift))];
      rowid[tid] = row;
      rsc[tid] = scaleArr[row];
    }
    __syncthreads();
  }
  const int rowq = tid >> 4;   // 0..31: rows 4*rowq..+3
  const int colq = tid & 15;   // cols {4c..4c+3, 64+4c..+3}
  float4 va[2], vw[2];
#pragma unroll
  for (int i = 0; i < 2; ++i) {
    int idx = tid + 512 * i;
    int row = idx >> 3, f4 = idx & 7;
    int grw = kept ? rowid[row] : tile * 128 + row;
    va[i] = *(const float4*)&A[(size_t)grw * 128 + 4 * f4];
  }
#pragma unroll
  for (int i = 0; i < 2; ++i) {
    int idx = tid + 512 * i;
    int kk = idx >> 5, cf = idx & 31;
    vw[i] = *(const float4*)&W[(size_t)kk * 128 + 4 * cf];
  }
#pragma unroll
  for (int i = 0; i < 2; ++i) {
    int idx = tid + 512 * i;
    int row = idx >> 3, f4 = idx & 7;
    Ast[0][(4 * f4 + 0) * AST + row] = va[i].x;
    Ast[0][(4 * f4 + 1) * AST + row] = va[i].y;
    Ast[0][(4 * f4 + 2) * AST + row] = va[i].z;
    Ast[0][(4 * f4 + 3) * AST + row] = va[i].w;
  }
#pragma unroll
  for (int i = 0; i < 2; ++i) {
    int idx = tid + 512 * i;
    int kk = idx >> 5, cf = idx & 31;
    *(float4*)&Ws[0][kk * 128 + 4 * cf] = vw[i];
  }
  __syncthreads();
  float acc[4][8] = {};
  for (int c = 0; c < 4; ++c) {
    int cur = c & 1;
    if (c < 3) {
      int k0n = 32 * (c + 1);
#pragma unroll
      for (int i = 0; i < 2; ++i) {
        int idx = tid + 512 * i;
        int row = idx >> 3, f4 = idx & 7;
        int grw = kept ? rowid[row] : tile * 128 + row;
        va[i] = *(const float4*)&A[(size_t)grw * 128 + k0n + 4 * f4];
      }
#pragma unroll
      for (int i = 0; i < 2; ++i) {
        int idx = tid + 512 * i;
        int kk = idx >> 5, cf = idx & 31;
        vw[i] = *(const float4*)&W[(size_t)(k0n + kk) * 128 + 4 * cf];
      }
    }
#pragma unroll 2
    for (int kk = 0; kk < 32; ++kk) {
      float4 a0 = *(const float4*)&Ast[cur][kk * AST + 4 * rowq];
      float4 w0 = *(const float4*)&Ws[cur][kk * 128 + 4 * colq];
      float4 w1 = *(const float4*)&Ws[cur][kk * 128 + 64 + 4 * colq];
      float a[4] = {a0.x, a0.y, a0.z, a0.w};
      float w[8] = {w0.x, w0.y, w0.z, w0.w, w1.x, w1.y, w1.z, w1.w};
#pragma unroll
      for (int r = 0; r < 4; ++r)
#pragma unroll
        for (int cc = 0; cc < 8; ++cc) acc[r][cc] += a[r] * w[cc];
    }
    // fused readout of this chunk's 32 feats from the staged tile
    if (kept) {
      int kkf = tid >> 4;            // feat within chunk, 0..31
      int r0 = (tid & 15) * 8;       // 8-row slice per thread
      float mxv = -INFINITY, smv = 0.f;
#pragma unroll
      for (int rr = 0; rr < 8; rr += 4) {
        float4 av = *(const float4*)&Ast[cur][kkf * AST + r0 + rr];
        float4 s4 = *(const float4*)&rsc[r0 + rr];
        float v0 = av.x * s4.x, v1 = av.y * s4.y;
        float v2 = av.z * s4.z, v3 = av.w * s4.w;
        mxv = fmaxf(fmaxf(fmaxf(mxv, v0), fmaxf(v1, v2)), v3);
        smv += v0 + v1 + v2 + v3;
      }
#pragma unroll
      for (int o = 8; o >= 1; o >>= 1) {
        mxv = fmaxf(mxv, __shfl_down(mxv, o, 16));
        smv += __shfl_down(smv, o, 16);
      }
      if ((tid & 15) == 0) {
        pmx[(size_t)tile * 128 + 32 * c + kkf] = mxv;
        psm[(size_t)tile * 128 + 32 * c + kkf] = smv;
      }
    }
    if (c < 3) {
      int nxt = cur ^ 1;
#pragma unroll
      for (int i = 0; i < 2; ++i) {
        int idx = tid + 512 * i;
        int row = idx >> 3, f4 = idx & 7;
        Ast[nxt][(4 * f4 + 0) * AST + row] = va[i].x;
        Ast[nxt][(4 * f4 + 1) * AST + row] = va[i].y;
        Ast[nxt][(4 * f4 + 2) * AST + row] = va[i].z;
        Ast[nxt][(4 * f4 + 3) * AST + row] = va[i].w;
      }
#pragma unroll
      for (int i = 0; i < 2; ++i) {
        int idx = tid + 512 * i;
        int kk = idx >> 5, cf = idx & 31;
        *(float4*)&Ws[nxt][kk * 128 + 4 * cf] = vw[i];
      }
      __syncthreads();
    }
  }
#pragma unroll
  for (int r = 0; r < 4; ++r) {
    int grw = kept ? rowid[4 * rowq + r] : tile * 128 + 4 * rowq + r;
    float* Crow = &C[(size_t)grw * 128];
    *(float4*)&Crow[4 * colq] = make_float4(acc[r][0], acc[r][1], acc[r][2], acc[r][3]);
    *(float4*)&Crow[64 + 4 * colq] = make_float4(acc[r][4], acc[r][5], acc[r][6], acc[r][7]);
  }
}

// ---- feature aggregation + bias + relu + fused score matvec (R16) ----------
__global__ __launch_bounds__(256) void k_agg(const float4* __restrict__ t4,
                                             const int* __restrict__ off,
                                             const int* __restrict__ srcp,
                                             const float* __restrict__ dinv,
                                             const float* __restrict__ ds,
                                             const float* __restrict__ sws,
                                             const float* __restrict__ bias,
                                             const float* __restrict__ Wp,
                                             float4* __restrict__ h4,
                                             float* __restrict__ t1,
                                             const int* __restrict__ kept,
                                             int kshift, int bpgsh) {
  int q = relabel(blockIdx.x, bpgsh) * 8 + (threadIdx.x >> 5);
  int node;
  if (kept) {
    int g = q >> kshift;
    node = kept[g * N_ + (q - (g << kshift))];
  } else {
    node = q;
  }
  const int lane = threadIdx.x & 31;
  const float dvi = dinv[node];
  float sw = sws[node];
  float4 self = t4[(size_t)node * 32 + lane];
  float4 acc = make_float4(sw * self.x, sw * self.y, sw * self.z, sw * self.w);
  int s = off[node], en = off[node + 1];
  int j = s;
  for (; j + 8 <= en; j += 8) {
    int sv[8];
    float cv[8];
#pragma unroll
    for (int i = 0; i < 8; ++i) sv[i] = srcp[j + i];
#pragma unroll
    for (int i = 0; i < 8; ++i) cv[i] = ds[sv[i]] * dvi;
#pragma unroll
    for (int i = 0; i < 8; ++i) {
      if (cv[i] != 0.f) {
        float4 r = t4[(size_t)sv[i] * 32 + lane];
        acc.x += cv[i] * r.x; acc.y += cv[i] * r.y;
        acc.z += cv[i] * r.z; acc.w += cv[i] * r.w;
      }
    }
  }
  for (; j < en; ++j) {
    int s0 = srcp[j];
    float c0 = ds[s0] * dvi;
    if (c0 != 0.f) {
      float4 r0 = t4[(size_t)s0 * 32 + lane];
      acc.x += c0 * r0.x; acc.y += c0 * r0.y; acc.z += c0 * r0.z; acc.w += c0 * r0.w;
    }
  }
  float4 b4 = ((const float4*)bias)[lane];
  acc.x = fmaxf(acc.x + b4.x, 0.f);
  acc.y = fmaxf(acc.y + b4.y, 0.f);
  acc.z = fmaxf(acc.z + b4.z, 0.f);
  acc.w = fmaxf(acc.w + b4.w, 0.f);
  h4[(size_t)node * 32 + lane] = acc;
  float4 wp = ((const float4*)Wp)[lane];
  float part = acc.x * wp.x + acc.y * wp.y + acc.z * wp.z + acc.w * wp.w;
#pragma unroll
  for (int o = 16; o > 0; o >>= 1) part += __shfl_down(part, o, 32);
  if (lane == 0) t1[node] = part;
}

// ---- score aggregation (pool phase A, extracted): 8 lanes/node -------------
// raw[n] = di^2*t1[n] + di*sum_nbr(dinv[s]*t1[s]) + bp. Dropped neighbors
// have dinv=0 -> contribute 0. Runs device-wide over active nodes.
__global__ __launch_bounds__(256) void k_score(const float* __restrict__ t1,
                                               const int* __restrict__ off,
                                               const int* __restrict__ srcp,
                                               const float* __restrict__ dinv,
                                               const float* __restrict__ bp,
                                               float* __restrict__ raw,
                                               const int* __restrict__ kept,
                                               int kshift, int bpgsh) {
  int q = relabel(blockIdx.x, bpgsh) * 32 + (threadIdx.x >> 3);
  int node;
  if (kept) {
    int g = q >> kshift;
    node = kept[g * N_ + (q - (g << kshift))];
  } else {
    node = q;
  }
  const int lane = threadIdx.x & 7;
  int s = off[node], en = off[node + 1];
  float a = 0.f;
  for (int j = s + lane; j < en; j += 8) {
    int sl = srcp[j];
    a += dinv[sl] * t1[sl];
  }
#pragma unroll
  for (int o = 4; o >= 1; o >>= 1) a += __shfl_down(a, o, 8);
  if (lane == 0) {
    float di = dinv[node];
    raw[node] = di * di * t1[node] + di * a + bp[0];
  }
}

// ---- next-layer norm (pool phase D, extracted): 8 lanes/node over NEW kept -
// d = 1 + sum_nbr kpmask[s]; dinv=1/sqrt(d); ds=dinv*sc; sws=dinv^2*sc.
__global__ __launch_bounds__(256) void k_norm(const int* __restrict__ off,
                                              const int* __restrict__ srcp,
                                              const float* __restrict__ kpmask,
                                              const float* __restrict__ scale,
                                              float* __restrict__ dinv,
                                              float* __restrict__ ds,
                                              float* __restrict__ sws,
                                              const int* __restrict__ kept,
                                              int kshift, int bpgsh) {
  int q = relabel(blockIdx.x, bpgsh) * 32 + (threadIdx.x >> 3);
  int g = q >> kshift;
  int node = kept[g * N_ + (q - (g << kshift))];
  const int lane = threadIdx.x & 7;
  int s = off[node], en = off[node + 1];
  float d = (lane == 0) ? 1.f : 0.f;
  for (int j = s + lane; j < en; j += 8) d += kpmask[srcp[j]];
#pragma unroll
  for (int o = 4; o >= 1; o >>= 1) d += __shfl_down(d, o, 8);
  if (lane == 0) {
    float di = 1.f / sqrtf(d);
    float sc = scale[node];
    dinv[node] = di;
    ds[node] = di * sc;
    sws[node] = di * di * sc;
  }
}

// ---- pool: radix top-k select + compact + mask writes (+readout+head) ------
// Edge loops removed (k_score before, k_norm after). Iterates active nodes
// only; writes kpmask and zeroes dinv/ds/sws/scale for dropped nodes.
__global__ __launch_bounds__(1024) void k_pool(const float* __restrict__ raw,
                                               float* __restrict__ dinv,
                                               float* __restrict__ ds,
                                               float* __restrict__ sws,
                                               float* __restrict__ scale,
                                               float* __restrict__ kpmask,
                                               int* __restrict__ kept,
                                               const float4* __restrict__ h4,
                                               float invk, int k,
                                               const int* __restrict__ inKept, int klen,
                                               const float* __restrict__ pmxA,
                                               const float* __restrict__ psmA,
                                               const float* __restrict__ pmxB,
                                               const float* __restrict__ psmB,
                                               const float* __restrict__ hW1,
                                               const float* __restrict__ hb1,
                                               const float* __restrict__ hW2,
                                               const float* __restrict__ hb2,
                                               const float* __restrict__ hW3,
                                               const float* __restrict__ hb3,
                                               float* __restrict__ out) {
  __shared__ float st1[2048];       // scale after selection (readout)
  __shared__ float skp[2048];
  __shared__ int skept[1024];
  __shared__ unsigned rephist[4096];  // 16 waves x 256 bins; reused as red[]
  __shared__ unsigned ebits[64];
  __shared__ int wsum[16];
  __shared__ unsigned bc_digit, bc_prev;
  __shared__ float gr[256], o1[128], o2[64], o3[NCLS];
  const int g = (blockIdx.x & 7) + 8 * (blockIdx.x >> 3);
  const int t = threadIdx.x;
  const int base = g * N_;
  st1[t] = 0.f;
  st1[t + 1024] = 0.f;
  skp[t] = 0.f;
  skp[t + 1024] = 0.f;
  if (t < 64) ebits[t] = 0u;
#pragma unroll
  for (int i = 0; i < 4; ++i) rephist[t + 1024 * i] = 0u;
  __syncthreads();
  int nodeq[2] = {-1, -1};
  float rawv[2] = {0.f, 0.f};
  unsigned key[2] = {0xFFFFFFFFu, 0xFFFFFFFFu};
#pragma unroll
  for (int q = 0; q < 2; ++q) {
    int i = t + q * 1024;
    if (i >= klen) continue;
    int n = inKept ? (inKept[base + i] - base) : i;
    nodeq[q] = n;
    float r = raw[base + n];
    rawv[q] = r;
    unsigned u = __float_as_uint(r);
    u = (u & 0x80000000u) ? ~u : (u | 0x80000000u);
    u = ~u;  // descending
    key[q] = u;
  }
  // radix-select k-th largest score
  unsigned prefix = 0u, rem = (unsigned)k;
  const int wv = t >> 6;
  for (int shift = 24; shift >= 0; shift -= 8) {
    unsigned mask = (shift == 24) ? 0u : (0xFFFFFFFFu << (shift + 8));
#pragma unroll
    for (int q = 0; q < 2; ++q)
      if (nodeq[q] >= 0 && (key[q] & mask) == prefix)
        atomicAdd(&rephist[(wv << 8) + ((key[q] >> shift) & 255u)], 1u);
    __syncthreads();
    unsigned binv = 0u, v = 0u;
    if (t < 256) {
#pragma unroll
      for (int w = 0; w < 16; ++w) binv += rephist[(w << 8) + t];
      v = binv;
#pragma unroll
      for (int o = 1; o < 64; o <<= 1) {
        unsigned nv = __shfl_up(v, o);
        if ((t & 63) >= o) v += nv;
      }
      if ((t & 63) == 63) wsum[t >> 6] = (int)v;
    }
    __syncthreads();
    if (t < 256) {
      unsigned pre = 0u;
      int w4 = t >> 6;
      for (int u = 0; u < w4; ++u) pre += (unsigned)wsum[u];
      unsigned inc = v + pre, exc = inc - binv;
      if (inc >= rem && exc < rem) { bc_digit = (unsigned)t; bc_prev = exc; }
    }
    __syncthreads();
    if (shift > 0) {
#pragma unroll
      for (int i = 0; i < 4; ++i) rephist[t + 1024 * i] = 0u;
    }
    __syncthreads();
    prefix |= bc_digit << shift;
    rem -= bc_prev;
  }
  const unsigned Tkey = prefix;
  const int need = (int)rem;  // ties, lowest index first
#pragma unroll
  for (int q = 0; q < 2; ++q) {
    int n = nodeq[q];
    if (n >= 0 && key[q] == Tkey) atomicOr(&ebits[n >> 5], 1u << (n & 31));
  }
  __syncthreads();
#pragma unroll
  for (int q = 0; q < 2; ++q) {
    int n = nodeq[q];
    if (n < 0) continue;
    float kp;
    if (key[q] < Tkey) {
      kp = 1.f;
    } else if (key[q] == Tkey) {
      int w = n >> 5;
      int rank = __popc(ebits[w] & ((1u << (n & 31)) - 1u));
      for (int u = 0; u < w; ++u) rank += __popc(ebits[u]);
      kp = (rank < need) ? 1.f : 0.f;
    } else {
      kp = 0.f;
    }
    skp[n] = kp;
    float sc = kp * tanhf(rawv[q]);
    st1[n] = sc;
    scale[base + n] = sc;
    kpmask[base + n] = kp;
    if (kp == 0.f) {            // dropped: zero masks for next layer's gathers
      dinv[base + n] = 0.f;
      ds[base + n] = 0.f;
      sws[base + n] = 0.f;
    }
  }
  __syncthreads();
  // compacted kept list -> global + LDS
  {
    int lane = t & 63, w = t >> 6;
    int a0 = (int)skp[2 * t], a1 = (int)skp[2 * t + 1];
    int ps = a0 + a1;
    int v = ps;
#pragma unroll
    for (int o = 1; o < 64; o <<= 1) {
      int nv = __shfl_up(v, o);
      if (lane >= o) v += nv;
    }
    if (lane == 63) wsum[w] = v;
    __syncthreads();
    if (t == 0) {
      int accv = 0;
      for (int i = 0; i < 16; ++i) { int tmp = wsum[i]; wsum[i] = accv; accv += tmp; }
    }
    __syncthreads();
    int excl = wsum[w] + v - ps;
    if (a0) { kept[base + excl] = base + 2 * t; skept[excl] = base + 2 * t; }
    if (a1) { kept[base + excl + a0] = base + 2 * t + 1; skept[excl + a0] = base + 2 * t + 1; }
  }
  if (!out) return;
  __syncthreads();
  // layer-3 readout over kept list
  const int lane = t & 31, ng = t >> 5;
  float4 mx = make_float4(-INFINITY, -INFINITY, -INFINITY, -INFINITY);
  float4 sm = make_float4(0.f, 0.f, 0.f, 0.f);
  for (int i = ng; i < k; i += 32) {
    int node = skept[i];
    float sc = st1[node - base];
    float4 v = h4[(size_t)node * 32 + lane];
    v.x *= sc; v.y *= sc; v.z *= sc; v.w *= sc;
    mx.x = fmaxf(mx.x, v.x); mx.y = fmaxf(mx.y, v.y);
    mx.z = fmaxf(mx.z, v.z); mx.w = fmaxf(mx.w, v.w);
    sm.x += v.x; sm.y += v.y; sm.z += v.z; sm.w += v.w;
  }
  float4* red = (float4*)rephist;
  for (int d = 16; d >= 1; d >>= 1) {
    if (ng >= d && ng < 2 * d) {
      red[(ng - d) * 32 + lane] = mx;
      red[512 + (ng - d) * 32 + lane] = sm;
    }
    __syncthreads();
    if (ng < d) {
      float4 omx = red[ng * 32 + lane];
      float4 osm = red[512 + ng * 32 + lane];
      mx.x = fmaxf(mx.x, omx.x); mx.y = fmaxf(mx.y, omx.y);
      mx.z = fmaxf(mx.z, omx.z); mx.w = fmaxf(mx.w, omx.w);
      sm.x += osm.x; sm.y += osm.y; sm.z += osm.z; sm.w += osm.w;
    }
    __syncthreads();
  }
  if (ng == 0) {
    gr[4 * lane + 0] = mx.x;
    gr[4 * lane + 1] = mx.y;
    gr[4 * lane + 2] = mx.z;
    gr[4 * lane + 3] = mx.w;
    gr[128 + 4 * lane + 0] = sm.x * invk;
    gr[128 + 4 * lane + 1] = sm.y * invk;
    gr[128 + 4 * lane + 2] = sm.z * invk;
    gr[128 + 4 * lane + 3] = sm.w * invk;
  }
  __syncthreads();
  // fused MLP head + log_softmax
  if (t < 128) {
    float mxA = -INFINITY, smA = 0.f;
#pragma unroll
    for (int p = 0; p < 8; ++p) {
      mxA = fmaxf(mxA, pmxA[(size_t)(g * 8 + p) * 128 + t]);
      smA += psmA[(size_t)(g * 8 + p) * 128 + t];
    }
    float mxB = -INFINITY, smB = 0.f;
#pragma unroll
    for (int p = 0; p < 4; ++p) {
      mxB = fmaxf(mxB, pmxB[(size_t)(g * 4 + p) * 128 + t]);
      smB += psmB[(size_t)(g * 4 + p) * 128 + t];
    }
    gr[t] += mxA + mxB;
    gr[t + 128] += smA * (1.f / 1024.f) + smB * (1.f / 512.f);
  }
  __syncthreads();
  if (t < 128) {
    float a = hb1[t];
    for (int kk = 0; kk < 256; ++kk) a += gr[kk] * hW1[kk * 128 + t];
    o1[t] = fmaxf(a, 0.f);
  }
  __syncthreads();
  if (t < 64) {
    float a2 = hb2[t];
    for (int kk = 0; kk < 128; ++kk) a2 += o1[kk] * hW2[kk * 64 + t];
    o2[t] = fmaxf(a2, 0.f);
  }
  __syncthreads();
  if (t < NCLS) {
    float a3 = hb3[t];
    for (int kk = 0; kk < 64; ++kk) a3 += o2[kk] * hW3[kk * NCLS + t];
    o3[t] = a3;
  }
  __syncthreads();
  if (t == 0) {
    float m = -INFINITY;
    for (int c = 0; c < NCLS; ++c) m = fmaxf(m, o3[c]);
    float sum = 0.f;
    for (int c = 0; c < NCLS; ++c) sum += expf(o3[c] - m);
    float lse = logf(sum);
    for (int c = 0; c < NCLS; ++c) out[g * NCLS + c] = o3[c] - m - lse;
  }
}

}  // namespace

extern "C" void kernel_launch(void* const* d_in, const int* in_sizes, int n_in,
                              void* d_out, int out_size, void* d_ws, size_t ws_size,
                              hipStream_t stream) {
  const float* x = (const float*)d_in[0];
  const int* ei = (const int*)d_in[1];
  const int* src = ei;
  const int* dst = ei + E_;
  const float* Wl[3]  = {(const float*)d_in[3], (const float*)d_in[7], (const float*)d_in[11]};
  const float* bl[3]  = {(const float*)d_in[4], (const float*)d_in[8], (const float*)d_in[12]};
  const float* Wpl[3] = {(const float*)d_in[5], (const float*)d_in[9], (const float*)d_in[13]};
  const float* bpl[3] = {(const float*)d_in[6], (const float*)d_in[10], (const float*)d_in[14]};
  const float* l1W = (const float*)d_in[15];
  const float* l1b = (const float*)d_in[16];
  const float* l2W = (const float*)d_in[17];
  const float* l2b = (const float*)d_in[18];
  const float* l3W = (const float*)d_in[19];
  const float* l3b = (const float*)d_in[20];

  char* p = (char*)d_ws;
  auto alloc = [&](size_t bytes) -> void* {
    void* r = (void*)p;
    p += (bytes + 255) & ~size_t(255);
    return r;
  };
  float* h      = (float*)alloc((size_t)NT * 128 * 4);
  float* t      = (float*)alloc((size_t)NT * 128 * 4);
  float* dinv   = (float*)alloc(NT * 4);
  float* ds     = (float*)alloc(NT * 4);
  float* sws    = (float*)alloc(NT * 4);
  float* scale  = (float*)alloc(NT * 4);
  float* t1     = (float*)alloc(NT * 4);
  float* raw    = (float*)alloc(NT * 4);
  float* kpmask = (float*)alloc(NT * 4);
  int*   srcp   = (int*)alloc(E_ * 4);
  int*   off    = (int*)alloc((NT + 1) * 4);
  int*   kept0  = (int*)alloc(NT * 4);
  int*   kept1  = (int*)alloc(NT * 4);
  int*   kept2  = (int*)alloc(NT * 4);
  float* pmxA   = (float*)alloc(256 * 128 * 4);
  float* psmA   = (float*)alloc(256 * 128 * 4);
  float* pmxB   = (float*)alloc(128 * 128 * 4);
  float* psmB   = (float*)alloc(128 * 128 * 4);

  int* keptL[3] = {kept0, kept1, kept2};
  const int K[3] = {1024, 512, 256};
  const int KSH[3] = {10, 9, 8};
  float* pmxL[3] = {nullptr, pmxA, pmxB};
  float* psmL[3] = {nullptr, psmA, psmB};

  const float* inF = x;
  for (int l = 0; l < 3; ++l) {
    const int* inKept = (l == 0) ? nullptr : keptL[l - 1];
    int inKsh = (l == 0) ? 11 : KSH[l - 1];
    int nrows = (l == 0) ? NT : B_ * K[l - 1];
    int mm_bpgsh = (l == 0) ? 4 : (l == 1 ? 3 : 2);   // 512/256/128 mm blocks
    int ag_bpgsh = (l == 0) ? 8 : (l == 1 ? 7 : 6);   // 8192/4096/2048 blocks
    int sc_bpgsh = (l == 0) ? 6 : (l == 1 ? 5 : 4);   // 2048/1024/512 blocks
    int nm_bpgsh = (l == 0) ? 5 : 4;                  // 1024/512 blocks
    int csrB = (l == 0) ? B_ : 0;                     // csr piggybacks on mm0
    int klen = (l == 0) ? N_ : K[l - 1];
    bool last = (l == 2);
    k_matmul<<<nrows / 128 + csrB, 512, 0, stream>>>(
        inF, Wl[l], t, inKept, inKsh, mm_bpgsh, scale, pmxL[l], psmL[l],
        src, dst, off, srcp, dinv, ds, sws, csrB);
    k_agg<<<nrows / 8, 256, 0, stream>>>((const float4*)t, off, srcp, dinv, ds, sws,
                                         bl[l], Wpl[l], (float4*)h, t1, inKept, inKsh,
                                         ag_bpgsh);
    k_score<<<nrows / 32, 256, 0, stream>>>(t1, off, srcp, dinv, bpl[l], raw,
                                            inKept, inKsh, sc_bpgsh);
    k_pool<<<B_, 1024, 0, stream>>>(raw, dinv, ds, sws, scale, kpmask,
                                    keptL[l], (const float4*)h,
                                    1.f / (float)K[l], K[l], inKept, klen,
                                    last ? pmxA : nullptr, last ? psmA : nullptr,
                                    last ? pmxB : nullptr, last ? psmB : nullptr,
                                    l1W, l1b, l2W, l2b, l3W, l3b,
                                    last ? (float*)d_out : nullptr);
    if (!last) {
      k_norm<<<(B_ * K[l]) / 32, 256, 0, stream>>>(off, srcp, kpmask, scale,
                                                   dinv, ds, sws, keptL[l],
                                                   KSH[l], nm_bpgsh);
    }
    inF = h;
  }
}

// Round 9
// 293.368 us; speedup vs baseline: 5.4113x; 1.0281x over previous
//
#include <hip/hip_runtime.h>
#include <math.h>

// ---------------------------------------------------------------------------
// SAGPool GNN forward: 3x [GCNConv -> SAGPool(top-k) -> readout] + MLP head.
// B=32 graphs x N=2048 nodes; E=524288; 128 feats; K = 1024/512/256.
// R21 changes vs R20 (301.6us; R16 best 296):
//   - k_norm piggybacked onto the NEXT layer's k_matmul grid as a 3rd block
//     role (blocks [csr | mm-tiles | norm]); norm is independent of mm
//     (reads pool(l) outputs, writes dinv/ds/sws consumed by agg(l+1)).
//     Dispatches 14 -> 12, norm's serial time hidden under mm.
//   - mm/csr/agg/score/pool bodies identical to R20.
// ---------------------------------------------------------------------------

namespace {

constexpr int B_  = 32;
constexpr int N_  = 2048;
constexpr int NT  = B_ * N_;        // 65536
constexpr int EPG = 16384;
constexpr int E_  = B_ * EPG;       // 524288
constexpr int NCLS = 10;
constexpr int AST = 132;            // A-tile LDS row stride (128 + 4 pad)

// logical block id -> tile, grouping graphs g%8 per XCD (id%8=XCD).
__device__ __forceinline__ int relabel(int bid, int bpgsh) {
  int x = bid & 7, slot = bid >> 3;
  int g = x + 8 * (slot >> bpgsh);
  return (g << bpgsh) + (slot & ((1 << bpgsh) - 1));
}

// ---- CSR build + layer-0 norm, 512-thread variant (runs inside mm0 grid) --
__device__ void csr_build(const int* __restrict__ src, const int* __restrict__ dst,
                          int* __restrict__ off, int* __restrict__ srcp,
                          float* __restrict__ dinv, float* __restrict__ ds,
                          float* __restrict__ sws, int* hist) {
  const int g = blockIdx.x;    // blocks 0..31, %8 = XCD = g%8
  const int t = threadIdx.x;   // 0..511
  const int base_n = g * N_;
  const int base_e = g * EPG;
  int* wsum8 = hist + 2048;
#pragma unroll
  for (int i = 0; i < 4; ++i) hist[t + 512 * i] = 0;
  __syncthreads();
  for (int i = 0; i < EPG / 512; i += 8) {
    int dd[8];
#pragma unroll
    for (int j = 0; j < 8; ++j) dd[j] = dst[base_e + t + 512 * (i + j)];
#pragma unroll
    for (int j = 0; j < 8; ++j) atomicAdd(&hist[dd[j] - base_n], 1);
  }
  __syncthreads();
  int a[4], ssum = 0;
#pragma unroll
  for (int i = 0; i < 4; ++i) { a[i] = hist[4 * t + i]; ssum += a[i]; }
  {
    int lane = t & 63, w = t >> 6;   // 8 waves
    int v = ssum;
#pragma unroll
    for (int o = 1; o < 64; o <<= 1) {
      int nv = __shfl_up(v, o);
      if (lane >= o) v += nv;
    }
    if (lane == 63) wsum8[w] = v;
    __syncthreads();
    if (t == 0) {
      int accv = 0;
      for (int i = 0; i < 8; ++i) { int tmp = wsum8[i]; wsum8[i] = accv; accv += tmp; }
    }
    __syncthreads();
    int run = wsum8[w] + v - ssum;
#pragma unroll
    for (int i = 0; i < 4; ++i) {
      int n = 4 * t + i;
      off[base_n + n] = base_e + run;
      hist[n] = run;                 // LDS cursor (own bins only: safe)
      float d0 = 1.f + (float)a[i];  // deg = 1 + indegree (layer-0 masks = 1)
      float di0 = 1.f / sqrtf(d0);
      dinv[base_n + n] = di0;
      ds[base_n + n] = di0;
      sws[base_n + n] = di0 * di0;
      run += a[i];
    }
    if (g == B_ - 1 && t == 0) off[NT] = E_;
  }
  __syncthreads();
  for (int i = 0; i < EPG / 512; i += 8) {
    int dd[8], ss[8];
#pragma unroll
    for (int j = 0; j < 8; ++j) {
      int e = base_e + t + 512 * (i + j);
      dd[j] = dst[e];
      ss[j] = src[e];
    }
#pragma unroll
    for (int j = 0; j < 8; ++j) {
      int slot = atomicAdd(&hist[dd[j] - base_n], 1);
      srcp[base_e + slot] = ss[j];
    }
  }
}

// ---- norm role (512 thr, 64 nodes x 8 lanes), piggybacked on mm(l+1) ------
// d = 1 + sum_nbr kpmask[s]; dinv=1/sqrt(d); ds=dinv*sc; sws=dinv^2*sc.
__device__ void norm_body(const int* __restrict__ off,
                          const int* __restrict__ srcp,
                          const float* __restrict__ kpmask,
                          const float* __restrict__ scale,
                          float* __restrict__ dinv,
                          float* __restrict__ ds,
                          float* __restrict__ sws,
                          const int* __restrict__ nkept,
                          int nkshift, int nbpgsh, int nb) {
  int q = relabel(nb, nbpgsh) * 64 + ((int)threadIdx.x >> 3);
  int g = q >> nkshift;
  int node = nkept[g * N_ + (q - (g << nkshift))];
  const int lane = threadIdx.x & 7;
  int s = off[node], en = off[node + 1];
  float d = (lane == 0) ? 1.f : 0.f;
  for (int j = s + lane; j < en; j += 8) d += kpmask[srcp[j]];
#pragma unroll
  for (int o = 4; o >= 1; o >>= 1) d += __shfl_down(d, o, 8);
  if (lane == 0) {
    float di = 1.f / sqrtf(d);
    float sc = scale[node];
    dinv[node] = di;
    ds[node] = di * sc;
    sws[node] = di * di * sc;
  }
}

// ---- dense matmul + fused readout; 3 block roles: [csr | mm | norm] --------
__global__ __launch_bounds__(512) void k_matmul(const float* __restrict__ A,
                                                const float* __restrict__ W,
                                                float* __restrict__ C,
                                                const int* __restrict__ kept,
                                                int kshift, int bpgsh, int mmBlocks,
                                                const float* __restrict__ scaleArr,
                                                float* __restrict__ pmx,
                                                float* __restrict__ psm,
                                                const int* __restrict__ src,
                                                const int* __restrict__ dst,
                                                int* __restrict__ off,
                                                int* __restrict__ srcp,
                                                float* __restrict__ dinvW,
                                                float* __restrict__ dsW,
                                                float* __restrict__ swsW,
                                                int csrBlocks,
                                                const float* __restrict__ kpmask,
                                                const int* __restrict__ nkept,
                                                int nkshift, int nbpgsh) {
  __shared__ float Ast[2][32 * AST];   // 33.8 KB
  __shared__ float Ws[2][32 * 128];    // 32.8 KB
  __shared__ int rowid[128];
  __shared__ float rsc[128];
  if ((int)blockIdx.x < csrBlocks) {
    csr_build(src, dst, off, srcp, dinvW, dsW, swsW, (int*)&Ast[0][0]);
    return;
  }
  if ((int)blockIdx.x >= csrBlocks + mmBlocks) {
    norm_body(off, srcp, kpmask, scaleArr, dinvW, dsW, swsW, nkept,
              nkshift, nbpgsh, (int)blockIdx.x - csrBlocks - mmBlocks);
    return;
  }
  const int tid = threadIdx.x;   // 0..511
  const int tile = relabel((int)blockIdx.x - csrBlocks, bpgsh);
  if (kept) {
    if (tid < 128) {
      int q = tile * 128 + tid;
      int g = q >> kshift;
      int row = kept[g * N_ + (q - (g << kshift))];
      rowid[tid] = row;
      rsc[tid] = scaleArr[row];
    }
    __syncthreads();
  }
  const int rowq = tid >> 4;   // 0..31: rows 4*rowq..+3
  const int colq = tid & 15;   // cols {4c..4c+3, 64+4c..+3}
  float4 va[2], vw[2];
#pragma unroll
  for (int i = 0; i < 2; ++i) {
    int idx = tid + 512 * i;
    int row = idx >> 3, f4 = idx & 7;
    int grw = kept ? rowid[row] : tile * 128 + row;
    va[i] = *(const float4*)&A[(size_t)grw * 128 + 4 * f4];
  }
#pragma unroll
  for (int i = 0; i < 2; ++i) {
    int idx = tid + 512 * i;
    int kk = idx >> 5, cf = idx & 31;
    vw[i] = *(const float4*)&W[(size_t)kk * 128 + 4 * cf];
  }
#pragma unroll
  for (int i = 0; i < 2; ++i) {
    int idx = tid + 512 * i;
    int row = idx >> 3, f4 = idx & 7;
    Ast[0][(4 * f4 + 0) * AST + row] = va[i].x;
    Ast[0][(4 * f4 + 1) * AST + row] = va[i].y;
    Ast[0][(4 * f4 + 2) * AST + row] = va[i].z;
    Ast[0][(4 * f4 + 3) * AST + row] = va[i].w;
  }
#pragma unroll
  for (int i = 0; i < 2; ++i) {
    int idx = tid + 512 * i;
    int kk = idx >> 5, cf = idx & 31;
    *(float4*)&Ws[0][kk * 128 + 4 * cf] = vw[i];
  }
  __syncthreads();
  float acc[4][8] = {};
  for (int c = 0; c < 4; ++c) {
    int cur = c & 1;
    if (c < 3) {
      int k0n = 32 * (c + 1);
#pragma unroll
      for (int i = 0; i < 2; ++i) {
        int idx = tid + 512 * i;
        int row = idx >> 3, f4 = idx & 7;
        int grw = kept ? rowid[row] : tile * 128 + row;
        va[i] = *(const float4*)&A[(size_t)grw * 128 + k0n + 4 * f4];
      }
#pragma unroll
      for (int i = 0; i < 2; ++i) {
        int idx = tid + 512 * i;
        int kk = idx >> 5, cf = idx & 31;
        vw[i] = *(const float4*)&W[(size_t)(k0n + kk) * 128 + 4 * cf];
      }
    }
#pragma unroll 2
    for (int kk = 0; kk < 32; ++kk) {
      float4 a0 = *(const float4*)&Ast[cur][kk * AST + 4 * rowq];
      float4 w0 = *(const float4*)&Ws[cur][kk * 128 + 4 * colq];
      float4 w1 = *(const float4*)&Ws[cur][kk * 128 + 64 + 4 * colq];
      float a[4] = {a0.x, a0.y, a0.z, a0.w};
      float w[8] = {w0.x, w0.y, w0.z, w0.w, w1.x, w1.y, w1.z, w1.w};
#pragma unroll
      for (int r = 0; r < 4; ++r)
#pragma unroll
        for (int cc = 0; cc < 8; ++cc) acc[r][cc] += a[r] * w[cc];
    }
    // fused readout of this chunk's 32 feats from the staged tile
    if (kept) {
      int kkf = tid >> 4;            // feat within chunk, 0..31
      int r0 = (tid & 15) * 8;       // 8-row slice per thread
      float mxv = -INFINITY, smv = 0.f;
#pragma unroll
      for (int rr = 0; rr < 8; rr += 4) {
        float4 av = *(const float4*)&Ast[cur][kkf * AST + r0 + rr];
        float4 s4 = *(const float4*)&rsc[r0 + rr];
        float v0 = av.x * s4.x, v1 = av.y * s4.y;
        float v2 = av.z * s4.z, v3 = av.w * s4.w;
        mxv = fmaxf(fmaxf(fmaxf(mxv, v0), fmaxf(v1, v2)), v3);
        smv += v0 + v1 + v2 + v3;
      }
#pragma unroll
      for (int o = 8; o >= 1; o >>= 1) {
        mxv = fmaxf(mxv, __shfl_down(mxv, o, 16));
        smv += __shfl_down(smv, o, 16);
      }
      if ((tid & 15) == 0) {
        pmx[(size_t)tile * 128 + 32 * c + kkf] = mxv;
        psm[(size_t)tile * 128 + 32 * c + kkf] = smv;
      }
    }
    if (c < 3) {
      int nxt = cur ^ 1;
#pragma unroll
      for (int i = 0; i < 2; ++i) {
        int idx = tid + 512 * i;
        int row = idx >> 3, f4 = idx & 7;
        Ast[nxt][(4 * f4 + 0) * AST + row] = va[i].x;
        Ast[nxt][(4 * f4 + 1) * AST + row] = va[i].y;
        Ast[nxt][(4 * f4 + 2) * AST + row] = va[i].z;
        Ast[nxt][(4 * f4 + 3) * AST + row] = va[i].w;
      }
#pragma unroll
      for (int i = 0; i < 2; ++i) {
        int idx = tid + 512 * i;
        int kk = idx >> 5, cf = idx & 31;
        *(float4*)&Ws[nxt][kk * 128 + 4 * cf] = vw[i];
      }
      __syncthreads();
    }
  }
#pragma unroll
  for (int r = 0; r < 4; ++r) {
    int grw = kept ? rowid[4 * rowq + r] : tile * 128 + 4 * rowq + r;
    float* Crow = &C[(size_t)grw * 128];
    *(float4*)&Crow[4 * colq] = make_float4(acc[r][0], acc[r][1], acc[r][2], acc[r][3]);
    *(float4*)&Crow[64 + 4 * colq] = make_float4(acc[r][4], acc[r][5], acc[r][6], acc[r][7]);
  }
}

// ---- feature aggregation + bias + relu + fused score matvec (R16) ----------
__global__ __launch_bounds__(256) void k_agg(const float4* __restrict__ t4,
                                             const int* __restrict__ off,
                                             const int* __restrict__ srcp,
                                             const float* __restrict__ dinv,
                                             const float* __restrict__ ds,
                                             const float* __restrict__ sws,
                                             const float* __restrict__ bias,
                                             const float* __restrict__ Wp,
                                             float4* __restrict__ h4,
                                             float* __restrict__ t1,
                                             const int* __restrict__ kept,
                                             int kshift, int bpgsh) {
  int q = relabel(blockIdx.x, bpgsh) * 8 + (threadIdx.x >> 5);
  int node;
  if (kept) {
    int g = q >> kshift;
    node = kept[g * N_ + (q - (g << kshift))];
  } else {
    node = q;
  }
  const int lane = threadIdx.x & 31;
  const float dvi = dinv[node];
  float sw = sws[node];
  float4 self = t4[(size_t)node * 32 + lane];
  float4 acc = make_float4(sw * self.x, sw * self.y, sw * self.z, sw * self.w);
  int s = off[node], en = off[node + 1];
  int j = s;
  for (; j + 8 <= en; j += 8) {
    int sv[8];
    float cv[8];
#pragma unroll
    for (int i = 0; i < 8; ++i) sv[i] = srcp[j + i];
#pragma unroll
    for (int i = 0; i < 8; ++i) cv[i] = ds[sv[i]] * dvi;
#pragma unroll
    for (int i = 0; i < 8; ++i) {
      if (cv[i] != 0.f) {
        float4 r = t4[(size_t)sv[i] * 32 + lane];
        acc.x += cv[i] * r.x; acc.y += cv[i] * r.y;
        acc.z += cv[i] * r.z; acc.w += cv[i] * r.w;
      }
    }
  }
  for (; j < en; ++j) {
    int s0 = srcp[j];
    float c0 = ds[s0] * dvi;
    if (c0 != 0.f) {
      float4 r0 = t4[(size_t)s0 * 32 + lane];
      acc.x += c0 * r0.x; acc.y += c0 * r0.y; acc.z += c0 * r0.z; acc.w += c0 * r0.w;
    }
  }
  float4 b4 = ((const float4*)bias)[lane];
  acc.x = fmaxf(acc.x + b4.x, 0.f);
  acc.y = fmaxf(acc.y + b4.y, 0.f);
  acc.z = fmaxf(acc.z + b4.z, 0.f);
  acc.w = fmaxf(acc.w + b4.w, 0.f);
  h4[(size_t)node * 32 + lane] = acc;
  float4 wp = ((const float4*)Wp)[lane];
  float part = acc.x * wp.x + acc.y * wp.y + acc.z * wp.z + acc.w * wp.w;
#pragma unroll
  for (int o = 16; o > 0; o >>= 1) part += __shfl_down(part, o, 32);
  if (lane == 0) t1[node] = part;
}

// ---- score aggregation (pool phase A, extracted): 8 lanes/node -------------
__global__ __launch_bounds__(256) void k_score(const float* __restrict__ t1,
                                               const int* __restrict__ off,
                                               const int* __restrict__ srcp,
                                               const float* __restrict__ dinv,
                                               const float* __restrict__ bp,
                                               float* __restrict__ raw,
                                               const int* __restrict__ kept,
                                               int kshift, int bpgsh) {
  int q = relabel(blockIdx.x, bpgsh) * 32 + (threadIdx.x >> 3);
  int node;
  if (kept) {
    int g = q >> kshift;
    node = kept[g * N_ + (q - (g << kshift))];
  } else {
    node = q;
  }
  const int lane = threadIdx.x & 7;
  int s = off[node], en = off[node + 1];
  float a = 0.f;
  for (int j = s + lane; j < en; j += 8) {
    int sl = srcp[j];
    a += dinv[sl] * t1[sl];
  }
#pragma unroll
  for (int o = 4; o >= 1; o >>= 1) a += __shfl_down(a, o, 8);
  if (lane == 0) {
    float di = dinv[node];
    raw[node] = di * di * t1[node] + di * a + bp[0];
  }
}

// ---- pool: radix top-k select + compact + mask writes (+readout+head) ------
__global__ __launch_bounds__(1024) void k_pool(const float* __restrict__ raw,
                                               float* __restrict__ dinv,
                                               float* __restrict__ ds,
                                               float* __restrict__ sws,
                                               float* __restrict__ scale,
                                               float* __restrict__ kpmask,
                                               int* __restrict__ kept,
                                               const float4* __restrict__ h4,
                                               float invk, int k,
                                               const int* __restrict__ inKept, int klen,
                                               const float* __restrict__ pmxA,
                                               const float* __restrict__ psmA,
                                               const float* __restrict__ pmxB,
                                               const float* __restrict__ psmB,
                                               const float* __restrict__ hW1,
                                               const float* __restrict__ hb1,
                                               const float* __restrict__ hW2,
                                               const float* __restrict__ hb2,
                                               const float* __restrict__ hW3,
                                               const float* __restrict__ hb3,
                                               float* __restrict__ out) {
  __shared__ float st1[2048];       // scale after selection (readout)
  __shared__ float skp[2048];
  __shared__ int skept[1024];
  __shared__ unsigned rephist[4096];  // 16 waves x 256 bins; reused as red[]
  __shared__ unsigned ebits[64];
  __shared__ int wsum[16];
  __shared__ unsigned bc_digit, bc_prev;
  __shared__ float gr[256], o1[128], o2[64], o3[NCLS];
  const int g = (blockIdx.x & 7) + 8 * (blockIdx.x >> 3);
  const int t = threadIdx.x;
  const int base = g * N_;
  st1[t] = 0.f;
  st1[t + 1024] = 0.f;
  skp[t] = 0.f;
  skp[t + 1024] = 0.f;
  if (t < 64) ebits[t] = 0u;
#pragma unroll
  for (int i = 0; i < 4; ++i) rephist[t + 1024 * i] = 0u;
  __syncthreads();
  int nodeq[2] = {-1, -1};
  float rawv[2] = {0.f, 0.f};
  unsigned key[2] = {0xFFFFFFFFu, 0xFFFFFFFFu};
#pragma unroll
  for (int q = 0; q < 2; ++q) {
    int i = t + q * 1024;
    if (i >= klen) continue;
    int n = inKept ? (inKept[base + i] - base) : i;
    nodeq[q] = n;
    float r = raw[base + n];
    rawv[q] = r;
    unsigned u = __float_as_uint(r);
    u = (u & 0x80000000u) ? ~u : (u | 0x80000000u);
    u = ~u;  // descending
    key[q] = u;
  }
  // radix-select k-th largest score
  unsigned prefix = 0u, rem = (unsigned)k;
  const int wv = t >> 6;
  for (int shift = 24; shift >= 0; shift -= 8) {
    unsigned mask = (shift == 24) ? 0u : (0xFFFFFFFFu << (shift + 8));
#pragma unroll
    for (int q = 0; q < 2; ++q)
      if (nodeq[q] >= 0 && (key[q] & mask) == prefix)
        atomicAdd(&rephist[(wv << 8) + ((key[q] >> shift) & 255u)], 1u);
    __syncthreads();
    unsigned binv = 0u, v = 0u;
    if (t < 256) {
#pragma unroll
      for (int w = 0; w < 16; ++w) binv += rephist[(w << 8) + t];
      v = binv;
#pragma unroll
      for (int o = 1; o < 64; o <<= 1) {
        unsigned nv = __shfl_up(v, o);
        if ((t & 63) >= o) v += nv;
      }
      if ((t & 63) == 63) wsum[t >> 6] = (int)v;
    }
    __syncthreads();
    if (t < 256) {
      unsigned pre = 0u;
      int w4 = t >> 6;
      for (int u = 0; u < w4; ++u) pre += (unsigned)wsum[u];
      unsigned inc = v + pre, exc = inc - binv;
      if (inc >= rem && exc < rem) { bc_digit = (unsigned)t; bc_prev = exc; }
    }
    __syncthreads();
    if (shift > 0) {
#pragma unroll
      for (int i = 0; i < 4; ++i) rephist[t + 1024 * i] = 0u;
    }
    __syncthreads();
    prefix |= bc_digit << shift;
    rem -= bc_prev;
  }
  const unsigned Tkey = prefix;
  const int need = (int)rem;  // ties, lowest index first
#pragma unroll
  for (int q = 0; q < 2; ++q) {
    int n = nodeq[q];
    if (n >= 0 && key[q] == Tkey) atomicOr(&ebits[n >> 5], 1u << (n & 31));
  }
  __syncthreads();
#pragma unroll
  for (int q = 0; q < 2; ++q) {
    int n = nodeq[q];
    if (n < 0) continue;
    float kp;
    if (key[q] < Tkey) {
      kp = 1.f;
    } else if (key[q] == Tkey) {
      int w = n >> 5;
      int rank = __popc(ebits[w] & ((1u << (n & 31)) - 1u));
      for (int u = 0; u < w; ++u) rank += __popc(ebits[u]);
      kp = (rank < need) ? 1.f : 0.f;
    } else {
      kp = 0.f;
    }
    skp[n] = kp;
    float sc = kp * tanhf(rawv[q]);
    st1[n] = sc;
    scale[base + n] = sc;
    kpmask[base + n] = kp;
    if (kp == 0.f) {            // dropped: zero masks for next layer's gathers
      dinv[base + n] = 0.f;
      ds[base + n] = 0.f;
      sws[base + n] = 0.f;
    }
  }
  __syncthreads();
  // compacted kept list -> global + LDS
  {
    int lane = t & 63, w = t >> 6;
    int a0 = (int)skp[2 * t], a1 = (int)skp[2 * t + 1];
    int ps = a0 + a1;
    int v = ps;
#pragma unroll
    for (int o = 1; o < 64; o <<= 1) {
      int nv = __shfl_up(v, o);
      if (lane >= o) v += nv;
    }
    if (lane == 63) wsum[w] = v;
    __syncthreads();
    if (t == 0) {
      int accv = 0;
      for (int i = 0; i < 16; ++i) { int tmp = wsum[i]; wsum[i] = accv; accv += tmp; }
    }
    __syncthreads();
    int excl = wsum[w] + v - ps;
    if (a0) { kept[base + excl] = base + 2 * t; skept[excl] = base + 2 * t; }
    if (a1) { kept[base + excl + a0] = base + 2 * t + 1; skept[excl + a0] = base + 2 * t + 1; }
  }
  if (!out) return;
  __syncthreads();
  // layer-3 readout over kept list
  const int lane = t & 31, ng = t >> 5;
  float4 mx = make_float4(-INFINITY, -INFINITY, -INFINITY, -INFINITY);
  float4 sm = make_float4(0.f, 0.f, 0.f, 0.f);
  for (int i = ng; i < k; i += 32) {
    int node = skept[i];
    float sc = st1[node - base];
    float4 v = h4[(size_t)node * 32 + lane];
    v.x *= sc; v.y *= sc; v.z *= sc; v.w *= sc;
    mx.x = fmaxf(mx.x, v.x); mx.y = fmaxf(mx.y, v.y);
    mx.z = fmaxf(mx.z, v.z); mx.w = fmaxf(mx.w, v.w);
    sm.x += v.x; sm.y += v.y; sm.z += v.z; sm.w += v.w;
  }
  float4* red = (float4*)rephist;
  for (int d = 16; d >= 1; d >>= 1) {
    if (ng >= d && ng < 2 * d) {
      red[(ng - d) * 32 + lane] = mx;
      red[512 + (ng - d) * 32 + lane] = sm;
    }
    __syncthreads();
    if (ng < d) {
      float4 omx = red[ng * 32 + lane];
      float4 osm = red[512 + ng * 32 + lane];
      mx.x = fmaxf(mx.x, omx.x); mx.y = fmaxf(mx.y, omx.y);
      mx.z = fmaxf(mx.z, omx.z); mx.w = fmaxf(mx.w, omx.w);
      sm.x += osm.x; sm.y += osm.y; sm.z += osm.z; sm.w += osm.w;
    }
    __syncthreads();
  }
  if (ng == 0) {
    gr[4 * lane + 0] = mx.x;
    gr[4 * lane + 1] = mx.y;
    gr[4 * lane + 2] = mx.z;
    gr[4 * lane + 3] = mx.w;
    gr[128 + 4 * lane + 0] = sm.x * invk;
    gr[128 + 4 * lane + 1] = sm.y * invk;
    gr[128 + 4 * lane + 2] = sm.z * invk;
    gr[128 + 4 * lane + 3] = sm.w * invk;
  }
  __syncthreads();
  // fused MLP head + log_softmax
  if (t < 128) {
    float mxA = -INFINITY, smA = 0.f;
#pragma unroll
    for (int p = 0; p < 8; ++p) {
      mxA = fmaxf(mxA, pmxA[(size_t)(g * 8 + p) * 128 + t]);
      smA += psmA[(size_t)(g * 8 + p) * 128 + t];
    }
    float mxB = -INFINITY, smB = 0.f;
#pragma unroll
    for (int p = 0; p < 4; ++p) {
      mxB = fmaxf(mxB, pmxB[(size_t)(g * 4 + p) * 128 + t]);
      smB += psmB[(size_t)(g * 4 + p) * 128 + t];
    }
    gr[t] += mxA + mxB;
    gr[t + 128] += smA * (1.f / 1024.f) + smB * (1.f / 512.f);
  }
  __syncthreads();
  if (t < 128) {
    float a = hb1[t];
    for (int kk = 0; kk < 256; ++kk) a += gr[kk] * hW1[kk * 128 + t];
    o1[t] = fmaxf(a, 0.f);
  }
  __syncthreads();
  if (t < 64) {
    float a2 = hb2[t];
    for (int kk = 0; kk < 128; ++kk) a2 += o1[kk] * hW2[kk * 64 + t];
    o2[t] = fmaxf(a2, 0.f);
  }
  __syncthreads();
  if (t < NCLS) {
    float a3 = hb3[t];
    for (int kk = 0; kk < 64; ++kk) a3 += o2[kk] * hW3[kk * NCLS + t];
    o3[t] = a3;
  }
  __syncthreads();
  if (t == 0) {
    float m = -INFINITY;
    for (int c = 0; c < NCLS; ++c) m = fmaxf(m, o3[c]);
    float sum = 0.f;
    for (int c = 0; c < NCLS; ++c) sum += expf(o3[c] - m);
    float lse = logf(sum);
    for (int c = 0; c < NCLS; ++c) out[g * NCLS + c] = o3[c] - m - lse;
  }
}

}  // namespace

extern "C" void kernel_launch(void* const* d_in, const int* in_sizes, int n_in,
                              void* d_out, int out_size, void* d_ws, size_t ws_size,
                              hipStream_t stream) {
  const float* x = (const float*)d_in[0];
  const int* ei = (const int*)d_in[1];
  const int* src = ei;
  const int* dst = ei + E_;
  const float* Wl[3]  = {(const float*)d_in[3], (const float*)d_in[7], (const float*)d_in[11]};
  const float* bl[3]  = {(const float*)d_in[4], (const float*)d_in[8], (const float*)d_in[12]};
  const float* Wpl[3] = {(const float*)d_in[5], (const float*)d_in[9], (const float*)d_in[13]};
  const float* bpl[3] = {(const float*)d_in[6], (const float*)d_in[10], (const float*)d_in[14]};
  const float* l1W = (const float*)d_in[15];
  const float* l1b = (const float*)d_in[16];
  const float* l2W = (const float*)d_in[17];
  const float* l2b = (const float*)d_in[18];
  const float* l3W = (const float*)d_in[19];
  const float* l3b = (const float*)d_in[20];

  char* p = (char*)d_ws;
  auto alloc = [&](size_t bytes) -> void* {
    void* r = (void*)p;
    p += (bytes + 255) & ~size_t(255);
    return r;
  };
  float* h      = (float*)alloc((size_t)NT * 128 * 4);
  float* t      = (float*)alloc((size_t)NT * 128 * 4);
  float* dinv   = (float*)alloc(NT * 4);
  float* ds     = (float*)alloc(NT * 4);
  float* sws    = (float*)alloc(NT * 4);
  float* scale  = (float*)alloc(NT * 4);
  float* t1     = (float*)alloc(NT * 4);
  float* raw    = (float*)alloc(NT * 4);
  float* kpmask = (float*)alloc(NT * 4);
  int*   srcp   = (int*)alloc(E_ * 4);
  int*   off    = (int*)alloc((NT + 1) * 4);
  int*   kept0  = (int*)alloc(NT * 4);
  int*   kept1  = (int*)alloc(NT * 4);
  int*   kept2  = (int*)alloc(NT * 4);
  float* pmxA   = (float*)alloc(256 * 128 * 4);
  float* psmA   = (float*)alloc(256 * 128 * 4);
  float* pmxB   = (float*)alloc(128 * 128 * 4);
  float* psmB   = (float*)alloc(128 * 128 * 4);

  int* keptL[3] = {kept0, kept1, kept2};
  const int K[3] = {1024, 512, 256};
  const int KSH[3] = {10, 9, 8};
  float* pmxL[3] = {nullptr, pmxA, pmxB};
  float* psmL[3] = {nullptr, psmA, psmB};

  const float* inF = x;
  for (int l = 0; l < 3; ++l) {
    const int* inKept = (l == 0) ? nullptr : keptL[l - 1];
    int inKsh = (l == 0) ? 11 : KSH[l - 1];
    int nrows = (l == 0) ? NT : B_ * K[l - 1];
    int mmB = nrows / 128;
    int mm_bpgsh = (l == 0) ? 4 : (l == 1 ? 3 : 2);   // 512/256/128 mm blocks
    int ag_bpgsh = (l == 0) ? 8 : (l == 1 ? 7 : 6);   // 8192/4096/2048 blocks
    int sc_bpgsh = (l == 0) ? 6 : (l == 1 ? 5 : 4);   // 2048/1024/512 blocks
    int csrB = (l == 0) ? B_ : 0;                     // csr piggybacks on mm0
    // norm of layer l-1 piggybacks on mm(l): 64 nodes/block (512 thr, 8 lanes)
    int normB = (l == 0) ? 0 : (B_ * K[l - 1]) / 64;  // 512 / 256 blocks
    int nbpgsh = (l == 1) ? 4 : 3;                    // 16 / 8 blocks per graph
    int klen = (l == 0) ? N_ : K[l - 1];
    bool last = (l == 2);
    k_matmul<<<csrB + mmB + normB, 512, 0, stream>>>(
        inF, Wl[l], t, inKept, inKsh, mm_bpgsh, mmB, scale, pmxL[l], psmL[l],
        src, dst, off, srcp, dinv, ds, sws, csrB,
        kpmask, inKept, inKsh, nbpgsh);
    k_agg<<<nrows / 8, 256, 0, stream>>>((const float4*)t, off, srcp, dinv, ds, sws,
                                         bl[l], Wpl[l], (float4*)h, t1, inKept, inKsh,
                                         ag_bpgsh);
    k_score<<<nrows / 32, 256, 0, stream>>>(t1, off, srcp, dinv, bpl[l], raw,
                                            inKept, inKsh, sc_bpgsh);
    k_pool<<<B_, 1024, 0, stream>>>(raw, dinv, ds, sws, scale, kpmask,
                                    keptL[l], (const float4*)h,
                                    1.f / (float)K[l], K[l], inKept, klen,
                                    last ? pmxA : nullptr, last ? psmA : nullptr,
                                    last ? pmxB : nullptr, last ? psmB : nullptr,
                                    l1W, l1b, l2W, l2b, l3W, l3b,
                                    last ? (float*)d_out : nullptr);
    inF = h;
  }
}

// Round 10
// 290.214 us; speedup vs baseline: 5.4702x; 1.0109x over previous
//
#include <hip/hip_runtime.h>
#include <math.h>

// ---------------------------------------------------------------------------
// SAGPool GNN forward: 3x [GCNConv -> SAGPool(top-k) -> readout] + MLP head.
// B=32 graphs x N=2048 nodes; E=524288; 128 feats; K = 1024/512/256.
// R22 changes vs R21 (293.4us best):
//   - NEW mm0-only kernel k_mm0: 256x128 tile / 512 thr / 8x8 per thread /
//     BK=32 dbuf (99KB LDS, 1 block/CU = 8 waves). 0.5 B/flop halves the
//     LDS-pipe load vs R16's 4x8 (cap 53%->75% VALUBusy). dbuf + reg
//     prefetch keeps latency hidden (R17's single-buf+4-wave failure mode
//     avoided). csr still piggybacked (blocks 0..31).
//   - l1/l2 mm, agg, score, pool, norm piggyback: byte-identical to R21.
// ---------------------------------------------------------------------------

namespace {

constexpr int B_  = 32;
constexpr int N_  = 2048;
constexpr int NT  = B_ * N_;        // 65536
constexpr int EPG = 16384;
constexpr int E_  = B_ * EPG;       // 524288
constexpr int NCLS = 10;
constexpr int AST = 132;            // 128-row A-tile stride (l1/l2 mm)
constexpr int AST2 = 260;           // 256-row A-tile stride (k_mm0)

// logical block id -> tile, grouping graphs g%8 per XCD (id%8=XCD).
__device__ __forceinline__ int relabel(int bid, int bpgsh) {
  int x = bid & 7, slot = bid >> 3;
  int g = x + 8 * (slot >> bpgsh);
  return (g << bpgsh) + (slot & ((1 << bpgsh) - 1));
}

// ---- CSR build + layer-0 norm, 512-thread variant (runs inside mm0 grid) --
__device__ void csr_build(const int* __restrict__ src, const int* __restrict__ dst,
                          int* __restrict__ off, int* __restrict__ srcp,
                          float* __restrict__ dinv, float* __restrict__ ds,
                          float* __restrict__ sws, int* hist) {
  const int g = blockIdx.x;    // blocks 0..31, %8 = XCD = g%8
  const int t = threadIdx.x;   // 0..511
  const int base_n = g * N_;
  const int base_e = g * EPG;
  int* wsum8 = hist + 2048;
#pragma unroll
  for (int i = 0; i < 4; ++i) hist[t + 512 * i] = 0;
  __syncthreads();
  for (int i = 0; i < EPG / 512; i += 8) {
    int dd[8];
#pragma unroll
    for (int j = 0; j < 8; ++j) dd[j] = dst[base_e + t + 512 * (i + j)];
#pragma unroll
    for (int j = 0; j < 8; ++j) atomicAdd(&hist[dd[j] - base_n], 1);
  }
  __syncthreads();
  int a[4], ssum = 0;
#pragma unroll
  for (int i = 0; i < 4; ++i) { a[i] = hist[4 * t + i]; ssum += a[i]; }
  {
    int lane = t & 63, w = t >> 6;   // 8 waves
    int v = ssum;
#pragma unroll
    for (int o = 1; o < 64; o <<= 1) {
      int nv = __shfl_up(v, o);
      if (lane >= o) v += nv;
    }
    if (lane == 63) wsum8[w] = v;
    __syncthreads();
    if (t == 0) {
      int accv = 0;
      for (int i = 0; i < 8; ++i) { int tmp = wsum8[i]; wsum8[i] = accv; accv += tmp; }
    }
    __syncthreads();
    int run = wsum8[w] + v - ssum;
#pragma unroll
    for (int i = 0; i < 4; ++i) {
      int n = 4 * t + i;
      off[base_n + n] = base_e + run;
      hist[n] = run;                 // LDS cursor (own bins only: safe)
      float d0 = 1.f + (float)a[i];  // deg = 1 + indegree (layer-0 masks = 1)
      float di0 = 1.f / sqrtf(d0);
      dinv[base_n + n] = di0;
      ds[base_n + n] = di0;
      sws[base_n + n] = di0 * di0;
      run += a[i];
    }
    if (g == B_ - 1 && t == 0) off[NT] = E_;
  }
  __syncthreads();
  for (int i = 0; i < EPG / 512; i += 8) {
    int dd[8], ss[8];
#pragma unroll
    for (int j = 0; j < 8; ++j) {
      int e = base_e + t + 512 * (i + j);
      dd[j] = dst[e];
      ss[j] = src[e];
    }
#pragma unroll
    for (int j = 0; j < 8; ++j) {
      int slot = atomicAdd(&hist[dd[j] - base_n], 1);
      srcp[base_e + slot] = ss[j];
    }
  }
}

// ---- layer-0 matmul: 256x128 tile / 512 thr / 8x8 per thread / BK=32 dbuf --
// 99KB LDS -> 1 block/CU (8 waves). Blocks [0,32) run csr_build.
__global__ __launch_bounds__(512) void k_mm0(const float* __restrict__ A,
                                             const float* __restrict__ W,
                                             float* __restrict__ C,
                                             const int* __restrict__ src,
                                             const int* __restrict__ dst,
                                             int* __restrict__ off,
                                             int* __restrict__ srcp,
                                             float* __restrict__ dinvW,
                                             float* __restrict__ dsW,
                                             float* __restrict__ swsW) {
  __shared__ float Ast[2][32 * AST2];  // 66.6 KB, [k][row] transposed
  __shared__ float Ws[2][32 * 128];    // 32.8 KB, [k][col]
  if ((int)blockIdx.x < 32) {
    csr_build(src, dst, off, srcp, dinvW, dsW, swsW, (int*)&Ast[0][0]);
    return;
  }
  const int tid = threadIdx.x;                        // 0..511
  const int tile = relabel((int)blockIdx.x - 32, 3);  // 8 tiles/graph
  const int row0 = tile * 256;
  const int rowq = tid >> 4;   // 0..31: rows 8*rowq..+7
  const int colq = tid & 15;   // cols {4c..4c+3, 64+4c..+3}
  float4 va[4], vw[2];
  // stage k-chunk 0: A 256x32 (2048 f4), W 32x128 (1024 f4)
#pragma unroll
  for (int i = 0; i < 4; ++i) {
    int idx = tid + 512 * i;
    int row = idx >> 3, f4 = idx & 7;
    va[i] = *(const float4*)&A[(size_t)(row0 + row) * 128 + 4 * f4];
  }
#pragma unroll
  for (int i = 0; i < 2; ++i) {
    int idx = tid + 512 * i;
    int kk = idx >> 5, cf = idx & 31;
    vw[i] = *(const float4*)&W[(size_t)kk * 128 + 4 * cf];
  }
#pragma unroll
  for (int i = 0; i < 4; ++i) {
    int idx = tid + 512 * i;
    int row = idx >> 3, f4 = idx & 7;
    Ast[0][(4 * f4 + 0) * AST2 + row] = va[i].x;
    Ast[0][(4 * f4 + 1) * AST2 + row] = va[i].y;
    Ast[0][(4 * f4 + 2) * AST2 + row] = va[i].z;
    Ast[0][(4 * f4 + 3) * AST2 + row] = va[i].w;
  }
#pragma unroll
  for (int i = 0; i < 2; ++i) {
    int idx = tid + 512 * i;
    int kk = idx >> 5, cf = idx & 31;
    *(float4*)&Ws[0][kk * 128 + 4 * cf] = vw[i];
  }
  __syncthreads();
  float acc[8][8] = {};
  for (int c = 0; c < 4; ++c) {
    int cur = c & 1;
    if (c < 3) {
      int k0n = 32 * (c + 1);
#pragma unroll
      for (int i = 0; i < 4; ++i) {
        int idx = tid + 512 * i;
        int row = idx >> 3, f4 = idx & 7;
        va[i] = *(const float4*)&A[(size_t)(row0 + row) * 128 + k0n + 4 * f4];
      }
#pragma unroll
      for (int i = 0; i < 2; ++i) {
        int idx = tid + 512 * i;
        int kk = idx >> 5, cf = idx & 31;
        vw[i] = *(const float4*)&W[(size_t)(k0n + kk) * 128 + 4 * cf];
      }
    }
#pragma unroll 2
    for (int kk = 0; kk < 32; ++kk) {
      float4 a0 = *(const float4*)&Ast[cur][kk * AST2 + 8 * rowq];
      float4 a1 = *(const float4*)&Ast[cur][kk * AST2 + 8 * rowq + 4];
      float4 w0 = *(const float4*)&Ws[cur][kk * 128 + 4 * colq];
      float4 w1 = *(const float4*)&Ws[cur][kk * 128 + 64 + 4 * colq];
      float a[8] = {a0.x, a0.y, a0.z, a0.w, a1.x, a1.y, a1.z, a1.w};
      float w[8] = {w0.x, w0.y, w0.z, w0.w, w1.x, w1.y, w1.z, w1.w};
#pragma unroll
      for (int r = 0; r < 8; ++r)
#pragma unroll
        for (int cc = 0; cc < 8; ++cc) acc[r][cc] += a[r] * w[cc];
    }
    if (c < 3) {
      int nxt = cur ^ 1;
#pragma unroll
      for (int i = 0; i < 4; ++i) {
        int idx = tid + 512 * i;
        int row = idx >> 3, f4 = idx & 7;
        Ast[nxt][(4 * f4 + 0) * AST2 + row] = va[i].x;
        Ast[nxt][(4 * f4 + 1) * AST2 + row] = va[i].y;
        Ast[nxt][(4 * f4 + 2) * AST2 + row] = va[i].z;
        Ast[nxt][(4 * f4 + 3) * AST2 + row] = va[i].w;
      }
#pragma unroll
      for (int i = 0; i < 2; ++i) {
        int idx = tid + 512 * i;
        int kk = idx >> 5, cf = idx & 31;
        *(float4*)&Ws[nxt][kk * 128 + 4 * cf] = vw[i];
      }
      __syncthreads();
    }
  }
#pragma unroll
  for (int r = 0; r < 8; ++r) {
    float* Crow = &C[(size_t)(row0 + 8 * rowq + r) * 128];
    *(float4*)&Crow[4 * colq] = make_float4(acc[r][0], acc[r][1], acc[r][2], acc[r][3]);
    *(float4*)&Crow[64 + 4 * colq] = make_float4(acc[r][4], acc[r][5], acc[r][6], acc[r][7]);
  }
}

// ---- norm role (512 thr, 64 nodes x 8 lanes), piggybacked on mm(l+1) ------
__device__ void norm_body(const int* __restrict__ off,
                          const int* __restrict__ srcp,
                          const float* __restrict__ kpmask,
                          const float* __restrict__ scale,
                          float* __restrict__ dinv,
                          float* __restrict__ ds,
                          float* __restrict__ sws,
                          const int* __restrict__ nkept,
                          int nkshift, int nbpgsh, int nb) {
  int q = relabel(nb, nbpgsh) * 64 + ((int)threadIdx.x >> 3);
  int g = q >> nkshift;
  int node = nkept[g * N_ + (q - (g << nkshift))];
  const int lane = threadIdx.x & 7;
  int s = off[node], en = off[node + 1];
  float d = (lane == 0) ? 1.f : 0.f;
  for (int j = s + lane; j < en; j += 8) d += kpmask[srcp[j]];
#pragma unroll
  for (int o = 4; o >= 1; o >>= 1) d += __shfl_down(d, o, 8);
  if (lane == 0) {
    float di = 1.f / sqrtf(d);
    float sc = scale[node];
    dinv[node] = di;
    ds[node] = di * sc;
    sws[node] = di * di * sc;
  }
}

// ---- l1/l2 dense matmul + fused readout; roles: [mm | norm] ----------------
__global__ __launch_bounds__(512) void k_matmul(const float* __restrict__ A,
                                                const float* __restrict__ W,
                                                float* __restrict__ C,
                                                const int* __restrict__ kept,
                                                int kshift, int bpgsh, int mmBlocks,
                                                const float* __restrict__ scaleArr,
                                                float* __restrict__ pmx,
                                                float* __restrict__ psm,
                                                const int* __restrict__ off,
                                                const int* __restrict__ srcp,
                                                float* __restrict__ dinvW,
                                                float* __restrict__ dsW,
                                                float* __restrict__ swsW,
                                                const float* __restrict__ kpmask,
                                                const int* __restrict__ nkept,
                                                int nkshift, int nbpgsh) {
  __shared__ float Ast[2][32 * AST];   // 33.8 KB
  __shared__ float Ws[2][32 * 128];    // 32.8 KB
  __shared__ int rowid[128];
  __shared__ float rsc[128];
  if ((int)blockIdx.x >= mmBlocks) {
    norm_body(off, srcp, kpmask, scaleArr, dinvW, dsW, swsW, nkept,
              nkshift, nbpgsh, (int)blockIdx.x - mmBlocks);
    return;
  }
  const int tid = threadIdx.x;   // 0..511
  const int tile = relabel((int)blockIdx.x, bpgsh);
  if (tid < 128) {
    int q = tile * 128 + tid;
    int g = q >> kshift;
    int row = kept[g * N_ + (q - (g << kshift))];
    rowid[tid] = row;
    rsc[tid] = scaleArr[row];
  }
  __syncthreads();
  const int rowq = tid >> 4;   // 0..31: rows 4*rowq..+3
  const int colq = tid & 15;   // cols {4c..4c+3, 64+4c..+3}
  float4 va[2], vw[2];
#pragma unroll
  for (int i = 0; i < 2; ++i) {
    int idx = tid + 512 * i;
    int row = idx >> 3, f4 = idx & 7;
    va[i] = *(const float4*)&A[(size_t)rowid[row] * 128 + 4 * f4];
  }
#pragma unroll
  for (int i = 0; i < 2; ++i) {
    int idx = tid + 512 * i;
    int kk = idx >> 5, cf = idx & 31;
    vw[i] = *(const float4*)&W[(size_t)kk * 128 + 4 * cf];
  }
#pragma unroll
  for (int i = 0; i < 2; ++i) {
    int idx = tid + 512 * i;
    int row = idx >> 3, f4 = idx & 7;
    Ast[0][(4 * f4 + 0) * AST + row] = va[i].x;
    Ast[0][(4 * f4 + 1) * AST + row] = va[i].y;
    Ast[0][(4 * f4 + 2) * AST + row] = va[i].z;
    Ast[0][(4 * f4 + 3) * AST + row] = va[i].w;
  }
#pragma unroll
  for (int i = 0; i < 2; ++i) {
    int idx = tid + 512 * i;
    int kk = idx >> 5, cf = idx & 31;
    *(float4*)&Ws[0][kk * 128 + 4 * cf] = vw[i];
  }
  __syncthreads();
  float acc[4][8] = {};
  for (int c = 0; c < 4; ++c) {
    int cur = c & 1;
    if (c < 3) {
      int k0n = 32 * (c + 1);
#pragma unroll
      for (int i = 0; i < 2; ++i) {
        int idx = tid + 512 * i;
        int row = idx >> 3, f4 = idx & 7;
        va[i] = *(const float4*)&A[(size_t)rowid[row] * 128 + k0n + 4 * f4];
      }
#pragma unroll
      for (int i = 0; i < 2; ++i) {
        int idx = tid + 512 * i;
        int kk = idx >> 5, cf = idx & 31;
        vw[i] = *(const float4*)&W[(size_t)(k0n + kk) * 128 + 4 * cf];
      }
    }
#pragma unroll 2
    for (int kk = 0; kk < 32; ++kk) {
      float4 a0 = *(const float4*)&Ast[cur][kk * AST + 4 * rowq];
      float4 w0 = *(const float4*)&Ws[cur][kk * 128 + 4 * colq];
      float4 w1 = *(const float4*)&Ws[cur][kk * 128 + 64 + 4 * colq];
      float a[4] = {a0.x, a0.y, a0.z, a0.w};
      float w[8] = {w0.x, w0.y, w0.z, w0.w, w1.x, w1.y, w1.z, w1.w};
#pragma unroll
      for (int r = 0; r < 4; ++r)
#pragma unroll
        for (int cc = 0; cc < 8; ++cc) acc[r][cc] += a[r] * w[cc];
    }
    // fused readout of this chunk's 32 feats from the staged tile
    {
      int kkf = tid >> 4;            // feat within chunk, 0..31
      int r0 = (tid & 15) * 8;       // 8-row slice per thread
      float mxv = -INFINITY, smv = 0.f;
#pragma unroll
      for (int rr = 0; rr < 8; rr += 4) {
        float4 av = *(const float4*)&Ast[cur][kkf * AST + r0 + rr];
        float4 s4 = *(const float4*)&rsc[r0 + rr];
        float v0 = av.x * s4.x, v1 = av.y * s4.y;
        float v2 = av.z * s4.z, v3 = av.w * s4.w;
        mxv = fmaxf(fmaxf(fmaxf(mxv, v0), fmaxf(v1, v2)), v3);
        smv += v0 + v1 + v2 + v3;
      }
#pragma unroll
      for (int o = 8; o >= 1; o >>= 1) {
        mxv = fmaxf(mxv, __shfl_down(mxv, o, 16));
        smv += __shfl_down(smv, o, 16);
      }
      if ((tid & 15) == 0) {
        pmx[(size_t)tile * 128 + 32 * c + kkf] = mxv;
        psm[(size_t)tile * 128 + 32 * c + kkf] = smv;
      }
    }
    if (c < 3) {
      int nxt = cur ^ 1;
#pragma unroll
      for (int i = 0; i < 2; ++i) {
        int idx = tid + 512 * i;
        int row = idx >> 3, f4 = idx & 7;
        Ast[nxt][(4 * f4 + 0) * AST + row] = va[i].x;
        Ast[nxt][(4 * f4 + 1) * AST + row] = va[i].y;
        Ast[nxt][(4 * f4 + 2) * AST + row] = va[i].z;
        Ast[nxt][(4 * f4 + 3) * AST + row] = va[i].w;
      }
#pragma unroll
      for (int i = 0; i < 2; ++i) {
        int idx = tid + 512 * i;
        int kk = idx >> 5, cf = idx & 31;
        *(float4*)&Ws[nxt][kk * 128 + 4 * cf] = vw[i];
      }
      __syncthreads();
    }
  }
#pragma unroll
  for (int r = 0; r < 4; ++r) {
    float* Crow = &C[(size_t)rowid[4 * rowq + r] * 128];
    *(float4*)&Crow[4 * colq] = make_float4(acc[r][0], acc[r][1], acc[r][2], acc[r][3]);
    *(float4*)&Crow[64 + 4 * colq] = make_float4(acc[r][4], acc[r][5], acc[r][6], acc[r][7]);
  }
}

// ---- feature aggregation + bias + relu + fused score matvec (R16) ----------
__global__ __launch_bounds__(256) void k_agg(const float4* __restrict__ t4,
                                             const int* __restrict__ off,
                                             const int* __restrict__ srcp,
                                             const float* __restrict__ dinv,
                                             const float* __restrict__ ds,
                                             const float* __restrict__ sws,
                                             const float* __restrict__ bias,
                                             const float* __restrict__ Wp,
                                             float4* __restrict__ h4,
                                             float* __restrict__ t1,
                                             const int* __restrict__ kept,
                                             int kshift, int bpgsh) {
  int q = relabel(blockIdx.x, bpgsh) * 8 + (threadIdx.x >> 5);
  int node;
  if (kept) {
    int g = q >> kshift;
    node = kept[g * N_ + (q - (g << kshift))];
  } else {
    node = q;
  }
  const int lane = threadIdx.x & 31;
  const float dvi = dinv[node];
  float sw = sws[node];
  float4 self = t4[(size_t)node * 32 + lane];
  float4 acc = make_float4(sw * self.x, sw * self.y, sw * self.z, sw * self.w);
  int s = off[node], en = off[node + 1];
  int j = s;
  for (; j + 8 <= en; j += 8) {
    int sv[8];
    float cv[8];
#pragma unroll
    for (int i = 0; i < 8; ++i) sv[i] = srcp[j + i];
#pragma unroll
    for (int i = 0; i < 8; ++i) cv[i] = ds[sv[i]] * dvi;
#pragma unroll
    for (int i = 0; i < 8; ++i) {
      if (cv[i] != 0.f) {
        float4 r = t4[(size_t)sv[i] * 32 + lane];
        acc.x += cv[i] * r.x; acc.y += cv[i] * r.y;
        acc.z += cv[i] * r.z; acc.w += cv[i] * r.w;
      }
    }
  }
  for (; j < en; ++j) {
    int s0 = srcp[j];
    float c0 = ds[s0] * dvi;
    if (c0 != 0.f) {
      float4 r0 = t4[(size_t)s0 * 32 + lane];
      acc.x += c0 * r0.x; acc.y += c0 * r0.y; acc.z += c0 * r0.z; acc.w += c0 * r0.w;
    }
  }
  float4 b4 = ((const float4*)bias)[lane];
  acc.x = fmaxf(acc.x + b4.x, 0.f);
  acc.y = fmaxf(acc.y + b4.y, 0.f);
  acc.z = fmaxf(acc.z + b4.z, 0.f);
  acc.w = fmaxf(acc.w + b4.w, 0.f);
  h4[(size_t)node * 32 + lane] = acc;
  float4 wp = ((const float4*)Wp)[lane];
  float part = acc.x * wp.x + acc.y * wp.y + acc.z * wp.z + acc.w * wp.w;
#pragma unroll
  for (int o = 16; o > 0; o >>= 1) part += __shfl_down(part, o, 32);
  if (lane == 0) t1[node] = part;
}

// ---- score aggregation: 8 lanes/node ---------------------------------------
__global__ __launch_bounds__(256) void k_score(const float* __restrict__ t1,
                                               const int* __restrict__ off,
                                               const int* __restrict__ srcp,
                                               const float* __restrict__ dinv,
                                               const float* __restrict__ bp,
                                               float* __restrict__ raw,
                                               const int* __restrict__ kept,
                                               int kshift, int bpgsh) {
  int q = relabel(blockIdx.x, bpgsh) * 32 + (threadIdx.x >> 3);
  int node;
  if (kept) {
    int g = q >> kshift;
    node = kept[g * N_ + (q - (g << kshift))];
  } else {
    node = q;
  }
  const int lane = threadIdx.x & 7;
  int s = off[node], en = off[node + 1];
  float a = 0.f;
  for (int j = s + lane; j < en; j += 8) {
    int sl = srcp[j];
    a += dinv[sl] * t1[sl];
  }
#pragma unroll
  for (int o = 4; o >= 1; o >>= 1) a += __shfl_down(a, o, 8);
  if (lane == 0) {
    float di = dinv[node];
    raw[node] = di * di * t1[node] + di * a + bp[0];
  }
}

// ---- pool: radix top-k select + compact + mask writes (+readout+head) ------
__global__ __launch_bounds__(1024) void k_pool(const float* __restrict__ raw,
                                               float* __restrict__ dinv,
                                               float* __restrict__ ds,
                                               float* __restrict__ sws,
                                               float* __restrict__ scale,
                                               float* __restrict__ kpmask,
                                               int* __restrict__ kept,
                                               const float4* __restrict__ h4,
                                               float invk, int k,
                                               const int* __restrict__ inKept, int klen,
                                               const float* __restrict__ pmxA,
                                               const float* __restrict__ psmA,
                                               const float* __restrict__ pmxB,
                                               const float* __restrict__ psmB,
                                               const float* __restrict__ hW1,
                                               const float* __restrict__ hb1,
                                               const float* __restrict__ hW2,
                                               const float* __restrict__ hb2,
                                               const float* __restrict__ hW3,
                                               const float* __restrict__ hb3,
                                               float* __restrict__ out) {
  __shared__ float st1[2048];       // scale after selection (readout)
  __shared__ float skp[2048];
  __shared__ int skept[1024];
  __shared__ unsigned rephist[4096];  // 16 waves x 256 bins; reused as red[]
  __shared__ unsigned ebits[64];
  __shared__ int wsum[16];
  __shared__ unsigned bc_digit, bc_prev;
  __shared__ float gr[256], o1[128], o2[64], o3[NCLS];
  const int g = (blockIdx.x & 7) + 8 * (blockIdx.x >> 3);
  const int t = threadIdx.x;
  const int base = g * N_;
  st1[t] = 0.f;
  st1[t + 1024] = 0.f;
  skp[t] = 0.f;
  skp[t + 1024] = 0.f;
  if (t < 64) ebits[t] = 0u;
#pragma unroll
  for (int i = 0; i < 4; ++i) rephist[t + 1024 * i] = 0u;
  __syncthreads();
  int nodeq[2] = {-1, -1};
  float rawv[2] = {0.f, 0.f};
  unsigned key[2] = {0xFFFFFFFFu, 0xFFFFFFFFu};
#pragma unroll
  for (int q = 0; q < 2; ++q) {
    int i = t + q * 1024;
    if (i >= klen) continue;
    int n = inKept ? (inKept[base + i] - base) : i;
    nodeq[q] = n;
    float r = raw[base + n];
    rawv[q] = r;
    unsigned u = __float_as_uint(r);
    u = (u & 0x80000000u) ? ~u : (u | 0x80000000u);
    u = ~u;  // descending
    key[q] = u;
  }
  // radix-select k-th largest score
  unsigned prefix = 0u, rem = (unsigned)k;
  const int wv = t >> 6;
  for (int shift = 24; shift >= 0; shift -= 8) {
    unsigned mask = (shift == 24) ? 0u : (0xFFFFFFFFu << (shift + 8));
#pragma unroll
    for (int q = 0; q < 2; ++q)
      if (nodeq[q] >= 0 && (key[q] & mask) == prefix)
        atomicAdd(&rephist[(wv << 8) + ((key[q] >> shift) & 255u)], 1u);
    __syncthreads();
    unsigned binv = 0u, v = 0u;
    if (t < 256) {
#pragma unroll
      for (int w = 0; w < 16; ++w) binv += rephist[(w << 8) + t];
      v = binv;
#pragma unroll
      for (int o = 1; o < 64; o <<= 1) {
        unsigned nv = __shfl_up(v, o);
        if ((t & 63) >= o) v += nv;
      }
      if ((t & 63) == 63) wsum[t >> 6] = (int)v;
    }
    __syncthreads();
    if (t < 256) {
      unsigned pre = 0u;
      int w4 = t >> 6;
      for (int u = 0; u < w4; ++u) pre += (unsigned)wsum[u];
      unsigned inc = v + pre, exc = inc - binv;
      if (inc >= rem && exc < rem) { bc_digit = (unsigned)t; bc_prev = exc; }
    }
    __syncthreads();
    if (shift > 0) {
#pragma unroll
      for (int i = 0; i < 4; ++i) rephist[t + 1024 * i] = 0u;
    }
    __syncthreads();
    prefix |= bc_digit << shift;
    rem -= bc_prev;
  }
  const unsigned Tkey = prefix;
  const int need = (int)rem;  // ties, lowest index first
#pragma unroll
  for (int q = 0; q < 2; ++q) {
    int n = nodeq[q];
    if (n >= 0 && key[q] == Tkey) atomicOr(&ebits[n >> 5], 1u << (n & 31));
  }
  __syncthreads();
#pragma unroll
  for (int q = 0; q < 2; ++q) {
    int n = nodeq[q];
    if (n < 0) continue;
    float kp;
    if (key[q] < Tkey) {
      kp = 1.f;
    } else if (key[q] == Tkey) {
      int w = n >> 5;
      int rank = __popc(ebits[w] & ((1u << (n & 31)) - 1u));
      for (int u = 0; u < w; ++u) rank += __popc(ebits[u]);
      kp = (rank < need) ? 1.f : 0.f;
    } else {
      kp = 0.f;
    }
    skp[n] = kp;
    float sc = kp * tanhf(rawv[q]);
    st1[n] = sc;
    scale[base + n] = sc;
    kpmask[base + n] = kp;
    if (kp == 0.f) {            // dropped: zero masks for next layer's gathers
      dinv[base + n] = 0.f;
      ds[base + n] = 0.f;
      sws[base + n] = 0.f;
    }
  }
  __syncthreads();
  // compacted kept list -> global + LDS
  {
    int lane = t & 63, w = t >> 6;
    int a0 = (int)skp[2 * t], a1 = (int)skp[2 * t + 1];
    int ps = a0 + a1;
    int v = ps;
#pragma unroll
    for (int o = 1; o < 64; o <<= 1) {
      int nv = __shfl_up(v, o);
      if (lane >= o) v += nv;
    }
    if (lane == 63) wsum[w] = v;
    __syncthreads();
    if (t == 0) {
      int accv = 0;
      for (int i = 0; i < 16; ++i) { int tmp = wsum[i]; wsum[i] = accv; accv += tmp; }
    }
    __syncthreads();
    int excl = wsum[w] + v - ps;
    if (a0) { kept[base + excl] = base + 2 * t; skept[excl] = base + 2 * t; }
    if (a1) { kept[base + excl + a0] = base + 2 * t + 1; skept[excl + a0] = base + 2 * t + 1; }
  }
  if (!out) return;
  __syncthreads();
  // layer-3 readout over kept list
  const int lane = t & 31, ng = t >> 5;
  float4 mx = make_float4(-INFINITY, -INFINITY, -INFINITY, -INFINITY);
  float4 sm = make_float4(0.f, 0.f, 0.f, 0.f);
  for (int i = ng; i < k; i += 32) {
    int node = skept[i];
    float sc = st1[node - base];
    float4 v = h4[(size_t)node * 32 + lane];
    v.x *= sc; v.y *= sc; v.z *= sc; v.w *= sc;
    mx.x = fmaxf(mx.x, v.x); mx.y = fmaxf(mx.y, v.y);
    mx.z = fmaxf(mx.z, v.z); mx.w = fmaxf(mx.w, v.w);
    sm.x += v.x; sm.y += v.y; sm.z += v.z; sm.w += v.w;
  }
  float4* red = (float4*)rephist;
  for (int d = 16; d >= 1; d >>= 1) {
    if (ng >= d && ng < 2 * d) {
      red[(ng - d) * 32 + lane] = mx;
      red[512 + (ng - d) * 32 + lane] = sm;
    }
    __syncthreads();
    if (ng < d) {
      float4 omx = red[ng * 32 + lane];
      float4 osm = red[512 + ng * 32 + lane];
      mx.x = fmaxf(mx.x, omx.x); mx.y = fmaxf(mx.y, omx.y);
      mx.z = fmaxf(mx.z, omx.z); mx.w = fmaxf(mx.w, omx.w);
      sm.x += osm.x; sm.y += osm.y; sm.z += osm.z; sm.w += osm.w;
    }
    __syncthreads();
  }
  if (ng == 0) {
    gr[4 * lane + 0] = mx.x;
    gr[4 * lane + 1] = mx.y;
    gr[4 * lane + 2] = mx.z;
    gr[4 * lane + 3] = mx.w;
    gr[128 + 4 * lane + 0] = sm.x * invk;
    gr[128 + 4 * lane + 1] = sm.y * invk;
    gr[128 + 4 * lane + 2] = sm.z * invk;
    gr[128 + 4 * lane + 3] = sm.w * invk;
  }
  __syncthreads();
  // fused MLP head + log_softmax
  if (t < 128) {
    float mxA = -INFINITY, smA = 0.f;
#pragma unroll
    for (int p = 0; p < 8; ++p) {
      mxA = fmaxf(mxA, pmxA[(size_t)(g * 8 + p) * 128 + t]);
      smA += psmA[(size_t)(g * 8 + p) * 128 + t];
    }
    float mxB = -INFINITY, smB = 0.f;
#pragma unroll
    for (int p = 0; p < 4; ++p) {
      mxB = fmaxf(mxB, pmxB[(size_t)(g * 4 + p) * 128 + t]);
      smB += psmB[(size_t)(g * 4 + p) * 128 + t];
    }
    gr[t] += mxA + mxB;
    gr[t + 128] += smA * (1.f / 1024.f) + smB * (1.f / 512.f);
  }
  __syncthreads();
  if (t < 128) {
    float a = hb1[t];
    for (int kk = 0; kk < 256; ++kk) a += gr[kk] * hW1[kk * 128 + t];
    o1[t] = fmaxf(a, 0.f);
  }
  __syncthreads();
  if (t < 64) {
    float a2 = hb2[t];
    for (int kk = 0; kk < 128; ++kk) a2 += o1[kk] * hW2[kk * 64 + t];
    o2[t] = fmaxf(a2, 0.f);
  }
  __syncthreads();
  if (t < NCLS) {
    float a3 = hb3[t];
    for (int kk = 0; kk < 64; ++kk) a3 += o2[kk] * hW3[kk * NCLS + t];
    o3[t] = a3;
  }
  __syncthreads();
  if (t == 0) {
    float m = -INFINITY;
    for (int c = 0; c < NCLS; ++c) m = fmaxf(m, o3[c]);
    float sum = 0.f;
    for (int c = 0; c < NCLS; ++c) sum += expf(o3[c] - m);
    float lse = logf(sum);
    for (int c = 0; c < NCLS; ++c) out[g * NCLS + c] = o3[c] - m - lse;
  }
}

}  // namespace

extern "C" void kernel_launch(void* const* d_in, const int* in_sizes, int n_in,
                              void* d_out, int out_size, void* d_ws, size_t ws_size,
                              hipStream_t stream) {
  const float* x = (const float*)d_in[0];
  const int* ei = (const int*)d_in[1];
  const int* src = ei;
  const int* dst = ei + E_;
  const float* Wl[3]  = {(const float*)d_in[3], (const float*)d_in[7], (const float*)d_in[11]};
  const float* bl[3]  = {(const float*)d_in[4], (const float*)d_in[8], (const float*)d_in[12]};
  const float* Wpl[3] = {(const float*)d_in[5], (const float*)d_in[9], (const float*)d_in[13]};
  const float* bpl[3] = {(const float*)d_in[6], (const float*)d_in[10], (const float*)d_in[14]};
  const float* l1W = (const float*)d_in[15];
  const float* l1b = (const float*)d_in[16];
  const float* l2W = (const float*)d_in[17];
  const float* l2b = (const float*)d_in[18];
  const float* l3W = (const float*)d_in[19];
  const float* l3b = (const float*)d_in[20];

  char* p = (char*)d_ws;
  auto alloc = [&](size_t bytes) -> void* {
    void* r = (void*)p;
    p += (bytes + 255) & ~size_t(255);
    return r;
  };
  float* h      = (float*)alloc((size_t)NT * 128 * 4);
  float* t      = (float*)alloc((size_t)NT * 128 * 4);
  float* dinv   = (float*)alloc(NT * 4);
  float* ds     = (float*)alloc(NT * 4);
  float* sws    = (float*)alloc(NT * 4);
  float* scale  = (float*)alloc(NT * 4);
  float* t1     = (float*)alloc(NT * 4);
  float* raw    = (float*)alloc(NT * 4);
  float* kpmask = (float*)alloc(NT * 4);
  int*   srcp   = (int*)alloc(E_ * 4);
  int*   off    = (int*)alloc((NT + 1) * 4);
  int*   kept0  = (int*)alloc(NT * 4);
  int*   kept1  = (int*)alloc(NT * 4);
  int*   kept2  = (int*)alloc(NT * 4);
  float* pmxA   = (float*)alloc(256 * 128 * 4);
  float* psmA   = (float*)alloc(256 * 128 * 4);
  float* pmxB   = (float*)alloc(128 * 128 * 4);
  float* psmB   = (float*)alloc(128 * 128 * 4);

  int* keptL[3] = {kept0, kept1, kept2};
  const int K[3] = {1024, 512, 256};
  const int KSH[3] = {10, 9, 8};
  float* pmxL[3] = {nullptr, pmxA, pmxB};
  float* psmL[3] = {nullptr, psmA, psmB};

  const float* inF = x;
  for (int l = 0; l < 3; ++l) {
    const int* inKept = (l == 0) ? nullptr : keptL[l - 1];
    int inKsh = (l == 0) ? 11 : KSH[l - 1];
    int nrows = (l == 0) ? NT : B_ * K[l - 1];
    int ag_bpgsh = (l == 0) ? 8 : (l == 1 ? 7 : 6);   // 8192/4096/2048 blocks
    int sc_bpgsh = (l == 0) ? 6 : (l == 1 ? 5 : 4);   // 2048/1024/512 blocks
    int klen = (l == 0) ? N_ : K[l - 1];
    bool last = (l == 2);
    if (l == 0) {
      // 256-row tiles: 256 mm blocks + 32 csr blocks, 512 thr, 8x8/thread
      k_mm0<<<32 + 256, 512, 0, stream>>>(x, Wl[0], t, src, dst, off, srcp,
                                          dinv, ds, sws);
    } else {
      int mmB = nrows / 128;
      int mm_bpgsh = (l == 1) ? 3 : 2;                // 256/128 mm blocks
      // norm of layer l-1 piggybacks: 64 nodes/block (512 thr, 8 lanes)
      int normB = (B_ * K[l - 1]) / 64;               // 512 / 256 blocks
      int nbpgsh = (l == 1) ? 4 : 3;                  // 16 / 8 blocks per graph
      k_matmul<<<mmB + normB, 512, 0, stream>>>(
          inF, Wl[l], t, inKept, inKsh, mm_bpgsh, mmB, scale, pmxL[l], psmL[l],
          off, srcp, dinv, ds, sws, kpmask, inKept, inKsh, nbpgsh);
    }
    k_agg<<<nrows / 8, 256, 0, stream>>>((const float4*)t, off, srcp, dinv, ds, sws,
                                         bl[l], Wpl[l], (float4*)h, t1, inKept, inKsh,
                                         ag_bpgsh);
    k_score<<<nrows / 32, 256, 0, stream>>>(t1, off, srcp, dinv, bpl[l], raw,
                                            inKept, inKsh, sc_bpgsh);
    k_pool<<<B_, 1024, 0, stream>>>(raw, dinv, ds, sws, scale, kpmask,
                                    keptL[l], (const float4*)h,
                                    1.f / (float)K[l], K[l], inKept, klen,
                                    last ? pmxA : nullptr, last ? psmA : nullptr,
                                    last ? pmxB : nullptr, last ? psmB : nullptr,
                                    l1W, l1b, l2W, l2b, l3W, l3b,
                                    last ? (float*)d_out : nullptr);
    inF = h;
  }
}

// Round 11
// 281.724 us; speedup vs baseline: 5.6350x; 1.0301x over previous
//
#include <hip/hip_runtime.h>
#include <math.h>

// ---------------------------------------------------------------------------
// SAGPool GNN forward: 3x [GCNConv -> SAGPool(top-k) -> readout] + MLP head.
// B=32 graphs x N=2048 nodes; E=524288; 128 feats; K = 1024/512/256.
// R23 changes vs R22 (290.2us; R21 293.4):
//   - mm0 REVERTED to R21's 128x128/512-thr/BK=32 kernel (per-dispatch
//     counters: 44us vs R22 k_mm0's 52us @ 1 block/CU latency wall).
//     mm geometry frozen permanently.
//   - k_pool radix select: 4 passes x 8bit with 16-way replicated hist ->
//     3 passes (11/11/10 bit) over ONE LDS-atomic histogram (2048 keys into
//     2048/1024 bins ~ 1 hit/bin; csr proves this pattern is cheap).
//     Removes one pass + the 16-replica reduction loops.
//   - csr/norm piggyback, agg, score, head: identical to R21.
// ---------------------------------------------------------------------------

namespace {

constexpr int B_  = 32;
constexpr int N_  = 2048;
constexpr int NT  = B_ * N_;        // 65536
constexpr int EPG = 16384;
constexpr int E_  = B_ * EPG;       // 524288
constexpr int NCLS = 10;
constexpr int AST = 132;            // A-tile LDS row stride (128 + 4 pad)

// logical block id -> tile, grouping graphs g%8 per XCD (id%8=XCD).
__device__ __forceinline__ int relabel(int bid, int bpgsh) {
  int x = bid & 7, slot = bid >> 3;
  int g = x + 8 * (slot >> bpgsh);
  return (g << bpgsh) + (slot & ((1 << bpgsh) - 1));
}

// ---- CSR build + layer-0 norm, 512-thread variant (runs inside mm0 grid) --
__device__ void csr_build(const int* __restrict__ src, const int* __restrict__ dst,
                          int* __restrict__ off, int* __restrict__ srcp,
                          float* __restrict__ dinv, float* __restrict__ ds,
                          float* __restrict__ sws, int* hist) {
  const int g = blockIdx.x;    // blocks 0..31, %8 = XCD = g%8
  const int t = threadIdx.x;   // 0..511
  const int base_n = g * N_;
  const int base_e = g * EPG;
  int* wsum8 = hist + 2048;
#pragma unroll
  for (int i = 0; i < 4; ++i) hist[t + 512 * i] = 0;
  __syncthreads();
  for (int i = 0; i < EPG / 512; i += 8) {
    int dd[8];
#pragma unroll
    for (int j = 0; j < 8; ++j) dd[j] = dst[base_e + t + 512 * (i + j)];
#pragma unroll
    for (int j = 0; j < 8; ++j) atomicAdd(&hist[dd[j] - base_n], 1);
  }
  __syncthreads();
  int a[4], ssum = 0;
#pragma unroll
  for (int i = 0; i < 4; ++i) { a[i] = hist[4 * t + i]; ssum += a[i]; }
  {
    int lane = t & 63, w = t >> 6;   // 8 waves
    int v = ssum;
#pragma unroll
    for (int o = 1; o < 64; o <<= 1) {
      int nv = __shfl_up(v, o);
      if (lane >= o) v += nv;
    }
    if (lane == 63) wsum8[w] = v;
    __syncthreads();
    if (t == 0) {
      int accv = 0;
      for (int i = 0; i < 8; ++i) { int tmp = wsum8[i]; wsum8[i] = accv; accv += tmp; }
    }
    __syncthreads();
    int run = wsum8[w] + v - ssum;
#pragma unroll
    for (int i = 0; i < 4; ++i) {
      int n = 4 * t + i;
      off[base_n + n] = base_e + run;
      hist[n] = run;                 // LDS cursor (own bins only: safe)
      float d0 = 1.f + (float)a[i];  // deg = 1 + indegree (layer-0 masks = 1)
      float di0 = 1.f / sqrtf(d0);
      dinv[base_n + n] = di0;
      ds[base_n + n] = di0;
      sws[base_n + n] = di0 * di0;
      run += a[i];
    }
    if (g == B_ - 1 && t == 0) off[NT] = E_;
  }
  __syncthreads();
  for (int i = 0; i < EPG / 512; i += 8) {
    int dd[8], ss[8];
#pragma unroll
    for (int j = 0; j < 8; ++j) {
      int e = base_e + t + 512 * (i + j);
      dd[j] = dst[e];
      ss[j] = src[e];
    }
#pragma unroll
    for (int j = 0; j < 8; ++j) {
      int slot = atomicAdd(&hist[dd[j] - base_n], 1);
      srcp[base_e + slot] = ss[j];
    }
  }
}

// ---- norm role (512 thr, 64 nodes x 8 lanes), piggybacked on mm(l+1) ------
__device__ void norm_body(const int* __restrict__ off,
                          const int* __restrict__ srcp,
                          const float* __restrict__ kpmask,
                          const float* __restrict__ scale,
                          float* __restrict__ dinv,
                          float* __restrict__ ds,
                          float* __restrict__ sws,
                          const int* __restrict__ nkept,
                          int nkshift, int nbpgsh, int nb) {
  int q = relabel(nb, nbpgsh) * 64 + ((int)threadIdx.x >> 3);
  int g = q >> nkshift;
  int node = nkept[g * N_ + (q - (g << nkshift))];
  const int lane = threadIdx.x & 7;
  int s = off[node], en = off[node + 1];
  float d = (lane == 0) ? 1.f : 0.f;
  for (int j = s + lane; j < en; j += 8) d += kpmask[srcp[j]];
#pragma unroll
  for (int o = 4; o >= 1; o >>= 1) d += __shfl_down(d, o, 8);
  if (lane == 0) {
    float di = 1.f / sqrtf(d);
    float sc = scale[node];
    dinv[node] = di;
    ds[node] = di * sc;
    sws[node] = di * di * sc;
  }
}

// ---- dense matmul + fused readout; 3 block roles: [csr | mm | norm] --------
__global__ __launch_bounds__(512) void k_matmul(const float* __restrict__ A,
                                                const float* __restrict__ W,
                                                float* __restrict__ C,
                                                const int* __restrict__ kept,
                                                int kshift, int bpgsh, int mmBlocks,
                                                const float* __restrict__ scaleArr,
                                                float* __restrict__ pmx,
                                                float* __restrict__ psm,
                                                const int* __restrict__ src,
                                                const int* __restrict__ dst,
                                                int* __restrict__ off,
                                                int* __restrict__ srcp,
                                                float* __restrict__ dinvW,
                                                float* __restrict__ dsW,
                                                float* __restrict__ swsW,
                                                int csrBlocks,
                                                const float* __restrict__ kpmask,
                                                const int* __restrict__ nkept,
                                                int nkshift, int nbpgsh) {
  __shared__ float Ast[2][32 * AST];   // 33.8 KB
  __shared__ float Ws[2][32 * 128];    // 32.8 KB
  __shared__ int rowid[128];
  __shared__ float rsc[128];
  if ((int)blockIdx.x < csrBlocks) {
    csr_build(src, dst, off, srcp, dinvW, dsW, swsW, (int*)&Ast[0][0]);
    return;
  }
  if ((int)blockIdx.x >= csrBlocks + mmBlocks) {
    norm_body(off, srcp, kpmask, scaleArr, dinvW, dsW, swsW, nkept,
              nkshift, nbpgsh, (int)blockIdx.x - csrBlocks - mmBlocks);
    return;
  }
  const int tid = threadIdx.x;   // 0..511
  const int tile = relabel((int)blockIdx.x - csrBlocks, bpgsh);
  if (kept) {
    if (tid < 128) {
      int q = tile * 128 + tid;
      int g = q >> kshift;
      int row = kept[g * N_ + (q - (g << kshift))];
      rowid[tid] = row;
      rsc[tid] = scaleArr[row];
    }
    __syncthreads();
  }
  const int rowq = tid >> 4;   // 0..31: rows 4*rowq..+3
  const int colq = tid & 15;   // cols {4c..4c+3, 64+4c..+3}
  float4 va[2], vw[2];
#pragma unroll
  for (int i = 0; i < 2; ++i) {
    int idx = tid + 512 * i;
    int row = idx >> 3, f4 = idx & 7;
    int grw = kept ? rowid[row] : tile * 128 + row;
    va[i] = *(const float4*)&A[(size_t)grw * 128 + 4 * f4];
  }
#pragma unroll
  for (int i = 0; i < 2; ++i) {
    int idx = tid + 512 * i;
    int kk = idx >> 5, cf = idx & 31;
    vw[i] = *(const float4*)&W[(size_t)kk * 128 + 4 * cf];
  }
#pragma unroll
  for (int i = 0; i < 2; ++i) {
    int idx = tid + 512 * i;
    int row = idx >> 3, f4 = idx & 7;
    Ast[0][(4 * f4 + 0) * AST + row] = va[i].x;
    Ast[0][(4 * f4 + 1) * AST + row] = va[i].y;
    Ast[0][(4 * f4 + 2) * AST + row] = va[i].z;
    Ast[0][(4 * f4 + 3) * AST + row] = va[i].w;
  }
#pragma unroll
  for (int i = 0; i < 2; ++i) {
    int idx = tid + 512 * i;
    int kk = idx >> 5, cf = idx & 31;
    *(float4*)&Ws[0][kk * 128 + 4 * cf] = vw[i];
  }
  __syncthreads();
  float acc[4][8] = {};
  for (int c = 0; c < 4; ++c) {
    int cur = c & 1;
    if (c < 3) {
      int k0n = 32 * (c + 1);
#pragma unroll
      for (int i = 0; i < 2; ++i) {
        int idx = tid + 512 * i;
        int row = idx >> 3, f4 = idx & 7;
        int grw = kept ? rowid[row] : tile * 128 + row;
        va[i] = *(const float4*)&A[(size_t)grw * 128 + k0n + 4 * f4];
      }
#pragma unroll
      for (int i = 0; i < 2; ++i) {
        int idx = tid + 512 * i;
        int kk = idx >> 5, cf = idx & 31;
        vw[i] = *(const float4*)&W[(size_t)(k0n + kk) * 128 + 4 * cf];
      }
    }
#pragma unroll 2
    for (int kk = 0; kk < 32; ++kk) {
      float4 a0 = *(const float4*)&Ast[cur][kk * AST + 4 * rowq];
      float4 w0 = *(const float4*)&Ws[cur][kk * 128 + 4 * colq];
      float4 w1 = *(const float4*)&Ws[cur][kk * 128 + 64 + 4 * colq];
      float a[4] = {a0.x, a0.y, a0.z, a0.w};
      float w[8] = {w0.x, w0.y, w0.z, w0.w, w1.x, w1.y, w1.z, w1.w};
#pragma unroll
      for (int r = 0; r < 4; ++r)
#pragma unroll
        for (int cc = 0; cc < 8; ++cc) acc[r][cc] += a[r] * w[cc];
    }
    // fused readout of this chunk's 32 feats from the staged tile
    if (kept) {
      int kkf = tid >> 4;            // feat within chunk, 0..31
      int r0 = (tid & 15) * 8;       // 8-row slice per thread
      float mxv = -INFINITY, smv = 0.f;
#pragma unroll
      for (int rr = 0; rr < 8; rr += 4) {
        float4 av = *(const float4*)&Ast[cur][kkf * AST + r0 + rr];
        float4 s4 = *(const float4*)&rsc[r0 + rr];
        float v0 = av.x * s4.x, v1 = av.y * s4.y;
        float v2 = av.z * s4.z, v3 = av.w * s4.w;
        mxv = fmaxf(fmaxf(fmaxf(mxv, v0), fmaxf(v1, v2)), v3);
        smv += v0 + v1 + v2 + v3;
      }
#pragma unroll
      for (int o = 8; o >= 1; o >>= 1) {
        mxv = fmaxf(mxv, __shfl_down(mxv, o, 16));
        smv += __shfl_down(smv, o, 16);
      }
      if ((tid & 15) == 0) {
        pmx[(size_t)tile * 128 + 32 * c + kkf] = mxv;
        psm[(size_t)tile * 128 + 32 * c + kkf] = smv;
      }
    }
    if (c < 3) {
      int nxt = cur ^ 1;
#pragma unroll
      for (int i = 0; i < 2; ++i) {
        int idx = tid + 512 * i;
        int row = idx >> 3, f4 = idx & 7;
        Ast[nxt][(4 * f4 + 0) * AST + row] = va[i].x;
        Ast[nxt][(4 * f4 + 1) * AST + row] = va[i].y;
        Ast[nxt][(4 * f4 + 2) * AST + row] = va[i].z;
        Ast[nxt][(4 * f4 + 3) * AST + row] = va[i].w;
      }
#pragma unroll
      for (int i = 0; i < 2; ++i) {
        int idx = tid + 512 * i;
        int kk = idx >> 5, cf = idx & 31;
        *(float4*)&Ws[nxt][kk * 128 + 4 * cf] = vw[i];
      }
      __syncthreads();
    }
  }
#pragma unroll
  for (int r = 0; r < 4; ++r) {
    int grw = kept ? rowid[4 * rowq + r] : tile * 128 + 4 * rowq + r;
    float* Crow = &C[(size_t)grw * 128];
    *(float4*)&Crow[4 * colq] = make_float4(acc[r][0], acc[r][1], acc[r][2], acc[r][3]);
    *(float4*)&Crow[64 + 4 * colq] = make_float4(acc[r][4], acc[r][5], acc[r][6], acc[r][7]);
  }
}

// ---- feature aggregation + bias + relu + fused score matvec (R16) ----------
__global__ __launch_bounds__(256) void k_agg(const float4* __restrict__ t4,
                                             const int* __restrict__ off,
                                             const int* __restrict__ srcp,
                                             const float* __restrict__ dinv,
                                             const float* __restrict__ ds,
                                             const float* __restrict__ sws,
                                             const float* __restrict__ bias,
                                             const float* __restrict__ Wp,
                                             float4* __restrict__ h4,
                                             float* __restrict__ t1,
                                             const int* __restrict__ kept,
                                             int kshift, int bpgsh) {
  int q = relabel(blockIdx.x, bpgsh) * 8 + (threadIdx.x >> 5);
  int node;
  if (kept) {
    int g = q >> kshift;
    node = kept[g * N_ + (q - (g << kshift))];
  } else {
    node = q;
  }
  const int lane = threadIdx.x & 31;
  const float dvi = dinv[node];
  float sw = sws[node];
  float4 self = t4[(size_t)node * 32 + lane];
  float4 acc = make_float4(sw * self.x, sw * self.y, sw * self.z, sw * self.w);
  int s = off[node], en = off[node + 1];
  int j = s;
  for (; j + 8 <= en; j += 8) {
    int sv[8];
    float cv[8];
#pragma unroll
    for (int i = 0; i < 8; ++i) sv[i] = srcp[j + i];
#pragma unroll
    for (int i = 0; i < 8; ++i) cv[i] = ds[sv[i]] * dvi;
#pragma unroll
    for (int i = 0; i < 8; ++i) {
      if (cv[i] != 0.f) {
        float4 r = t4[(size_t)sv[i] * 32 + lane];
        acc.x += cv[i] * r.x; acc.y += cv[i] * r.y;
        acc.z += cv[i] * r.z; acc.w += cv[i] * r.w;
      }
    }
  }
  for (; j < en; ++j) {
    int s0 = srcp[j];
    float c0 = ds[s0] * dvi;
    if (c0 != 0.f) {
      float4 r0 = t4[(size_t)s0 * 32 + lane];
      acc.x += c0 * r0.x; acc.y += c0 * r0.y; acc.z += c0 * r0.z; acc.w += c0 * r0.w;
    }
  }
  float4 b4 = ((const float4*)bias)[lane];
  acc.x = fmaxf(acc.x + b4.x, 0.f);
  acc.y = fmaxf(acc.y + b4.y, 0.f);
  acc.z = fmaxf(acc.z + b4.z, 0.f);
  acc.w = fmaxf(acc.w + b4.w, 0.f);
  h4[(size_t)node * 32 + lane] = acc;
  float4 wp = ((const float4*)Wp)[lane];
  float part = acc.x * wp.x + acc.y * wp.y + acc.z * wp.z + acc.w * wp.w;
#pragma unroll
  for (int o = 16; o > 0; o >>= 1) part += __shfl_down(part, o, 32);
  if (lane == 0) t1[node] = part;
}

// ---- score aggregation: 8 lanes/node ---------------------------------------
__global__ __launch_bounds__(256) void k_score(const float* __restrict__ t1,
                                               const int* __restrict__ off,
                                               const int* __restrict__ srcp,
                                               const float* __restrict__ dinv,
                                               const float* __restrict__ bp,
                                               float* __restrict__ raw,
                                               const int* __restrict__ kept,
                                               int kshift, int bpgsh) {
  int q = relabel(blockIdx.x, bpgsh) * 32 + (threadIdx.x >> 3);
  int node;
  if (kept) {
    int g = q >> kshift;
    node = kept[g * N_ + (q - (g << kshift))];
  } else {
    node = q;
  }
  const int lane = threadIdx.x & 7;
  int s = off[node], en = off[node + 1];
  float a = 0.f;
  for (int j = s + lane; j < en; j += 8) {
    int sl = srcp[j];
    a += dinv[sl] * t1[sl];
  }
#pragma unroll
  for (int o = 4; o >= 1; o >>= 1) a += __shfl_down(a, o, 8);
  if (lane == 0) {
    float di = dinv[node];
    raw[node] = di * di * t1[node] + di * a + bp[0];
  }
}

// ---- pool: 3-pass radix top-k + compact + mask writes (+readout+head) ------
__global__ __launch_bounds__(1024) void k_pool(const float* __restrict__ raw,
                                               float* __restrict__ dinv,
                                               float* __restrict__ ds,
                                               float* __restrict__ sws,
                                               float* __restrict__ scale,
                                               float* __restrict__ kpmask,
                                               int* __restrict__ kept,
                                               const float4* __restrict__ h4,
                                               float invk, int k,
                                               const int* __restrict__ inKept, int klen,
                                               const float* __restrict__ pmxA,
                                               const float* __restrict__ psmA,
                                               const float* __restrict__ pmxB,
                                               const float* __restrict__ psmB,
                                               const float* __restrict__ hW1,
                                               const float* __restrict__ hb1,
                                               const float* __restrict__ hW2,
                                               const float* __restrict__ hb2,
                                               const float* __restrict__ hW3,
                                               const float* __restrict__ hb3,
                                               float* __restrict__ out) {
  __shared__ float st1[2048];       // scale after selection (readout)
  __shared__ float skp[2048];
  __shared__ int skept[1024];
  __shared__ unsigned rephist[4096];  // radix bins; reused as red[] in readout
  __shared__ unsigned ebits[64];
  __shared__ int wsum[16];
  __shared__ unsigned bc_digit, bc_prev;
  __shared__ float gr[256], o1[128], o2[64], o3[NCLS];
  const int g = (blockIdx.x & 7) + 8 * (blockIdx.x >> 3);
  const int t = threadIdx.x;
  const int base = g * N_;
  st1[t] = 0.f;
  st1[t + 1024] = 0.f;
  skp[t] = 0.f;
  skp[t + 1024] = 0.f;
  if (t < 64) ebits[t] = 0u;
  __syncthreads();
  int nodeq[2] = {-1, -1};
  float rawv[2] = {0.f, 0.f};
  unsigned key[2] = {0xFFFFFFFFu, 0xFFFFFFFFu};
#pragma unroll
  for (int q = 0; q < 2; ++q) {
    int i = t + q * 1024;
    if (i >= klen) continue;
    int n = inKept ? (inKept[base + i] - base) : i;
    nodeq[q] = n;
    float r = raw[base + n];
    rawv[q] = r;
    unsigned u = __float_as_uint(r);
    u = (u & 0x80000000u) ? ~u : (u | 0x80000000u);
    u = ~u;  // descending
    key[q] = u;
  }
  // 3-pass radix select of k-th largest: bits [31:21], [20:10], [9:0].
  // Single LDS-atomic histogram (2048 keys -> ~1 hit/bin).
  unsigned prefix = 0u, rem = (unsigned)k;
  const int SH0 = 21, SH1 = 10, SH2 = 0;
  for (int p = 0; p < 3; ++p) {
    const int shift = (p == 0) ? SH0 : (p == 1 ? SH1 : SH2);
    const int nb = (p == 2) ? 1024 : 2048;
    const unsigned mask = (p == 0) ? 0u
                        : (p == 1 ? (0xFFFFFFFFu << SH0) : (0xFFFFFFFFu << SH1));
    rephist[t] = 0u;
    rephist[t + 1024] = 0u;
    __syncthreads();
#pragma unroll
    for (int q = 0; q < 2; ++q)
      if (nodeq[q] >= 0 && (key[q] & mask) == prefix)
        atomicAdd(&rephist[(key[q] >> shift) & (unsigned)(nb - 1)], 1u);
    __syncthreads();
    unsigned b0, b1;
    if (nb == 2048) { b0 = rephist[2 * t]; b1 = rephist[2 * t + 1]; }
    else           { b0 = rephist[t];     b1 = 0u; }
    unsigned ps = b0 + b1;
    {
      int lane = t & 63, w = t >> 6;
      unsigned v = ps;
#pragma unroll
      for (int o = 1; o < 64; o <<= 1) {
        unsigned nv = __shfl_up(v, o);
        if (lane >= o) v += nv;
      }
      if (lane == 63) wsum[w] = (int)v;
      __syncthreads();
      if (t == 0) {
        int accv = 0;
        for (int i = 0; i < 16; ++i) { int tmp = wsum[i]; wsum[i] = accv; accv += tmp; }
      }
      __syncthreads();
      unsigned exc = (unsigned)wsum[w] + v - ps;
      if (exc < rem && exc + b0 >= rem) {
        bc_digit = (unsigned)((nb == 2048) ? 2 * t : t);
        bc_prev = exc;
      }
      if (nb == 2048 && exc + b0 < rem && exc + b0 + b1 >= rem) {
        bc_digit = (unsigned)(2 * t + 1);
        bc_prev = exc + b0;
      }
    }
    __syncthreads();
    prefix |= bc_digit << shift;
    rem -= bc_prev;
  }
  const unsigned Tkey = prefix;
  const int need = (int)rem;  // ties, lowest index first
#pragma unroll
  for (int q = 0; q < 2; ++q) {
    int n = nodeq[q];
    if (n >= 0 && key[q] == Tkey) atomicOr(&ebits[n >> 5], 1u << (n & 31));
  }
  __syncthreads();
#pragma unroll
  for (int q = 0; q < 2; ++q) {
    int n = nodeq[q];
    if (n < 0) continue;
    float kp;
    if (key[q] < Tkey) {
      kp = 1.f;
    } else if (key[q] == Tkey) {
      int w = n >> 5;
      int rank = __popc(ebits[w] & ((1u << (n & 31)) - 1u));
      for (int u = 0; u < w; ++u) rank += __popc(ebits[u]);
      kp = (rank < need) ? 1.f : 0.f;
    } else {
      kp = 0.f;
    }
    skp[n] = kp;
    float sc = kp * tanhf(rawv[q]);
    st1[n] = sc;
    scale[base + n] = sc;
    kpmask[base + n] = kp;
    if (kp == 0.f) {            // dropped: zero masks for next layer's gathers
      dinv[base + n] = 0.f;
      ds[base + n] = 0.f;
      sws[base + n] = 0.f;
    }
  }
  __syncthreads();
  // compacted kept list -> global + LDS
  {
    int lane = t & 63, w = t >> 6;
    int a0 = (int)skp[2 * t], a1 = (int)skp[2 * t + 1];
    int ps = a0 + a1;
    int v = ps;
#pragma unroll
    for (int o = 1; o < 64; o <<= 1) {
      int nv = __shfl_up(v, o);
      if (lane >= o) v += nv;
    }
    if (lane == 63) wsum[w] = v;
    __syncthreads();
    if (t == 0) {
      int accv = 0;
      for (int i = 0; i < 16; ++i) { int tmp = wsum[i]; wsum[i] = accv; accv += tmp; }
    }
    __syncthreads();
    int excl = wsum[w] + v - ps;
    if (a0) { kept[base + excl] = base + 2 * t; skept[excl] = base + 2 * t; }
    if (a1) { kept[base + excl + a0] = base + 2 * t + 1; skept[excl + a0] = base + 2 * t + 1; }
  }
  if (!out) return;
  __syncthreads();
  // layer-3 readout over kept list
  const int lane = t & 31, ng = t >> 5;
  float4 mx = make_float4(-INFINITY, -INFINITY, -INFINITY, -INFINITY);
  float4 sm = make_float4(0.f, 0.f, 0.f, 0.f);
  for (int i = ng; i < k; i += 32) {
    int node = skept[i];
    float sc = st1[node - base];
    float4 v = h4[(size_t)node * 32 + lane];
    v.x *= sc; v.y *= sc; v.z *= sc; v.w *= sc;
    mx.x = fmaxf(mx.x, v.x); mx.y = fmaxf(mx.y, v.y);
    mx.z = fmaxf(mx.z, v.z); mx.w = fmaxf(mx.w, v.w);
    sm.x += v.x; sm.y += v.y; sm.z += v.z; sm.w += v.w;
  }
  float4* red = (float4*)rephist;
  for (int d = 16; d >= 1; d >>= 1) {
    if (ng >= d && ng < 2 * d) {
      red[(ng - d) * 32 + lane] = mx;
      red[512 + (ng - d) * 32 + lane] = sm;
    }
    __syncthreads();
    if (ng < d) {
      float4 omx = red[ng * 32 + lane];
      float4 osm = red[512 + ng * 32 + lane];
      mx.x = fmaxf(mx.x, omx.x); mx.y = fmaxf(mx.y, omx.y);
      mx.z = fmaxf(mx.z, omx.z); mx.w = fmaxf(mx.w, omx.w);
      sm.x += osm.x; sm.y += osm.y; sm.z += osm.z; sm.w += osm.w;
    }
    __syncthreads();
  }
  if (ng == 0) {
    gr[4 * lane + 0] = mx.x;
    gr[4 * lane + 1] = mx.y;
    gr[4 * lane + 2] = mx.z;
    gr[4 * lane + 3] = mx.w;
    gr[128 + 4 * lane + 0] = sm.x * invk;
    gr[128 + 4 * lane + 1] = sm.y * invk;
    gr[128 + 4 * lane + 2] = sm.z * invk;
    gr[128 + 4 * lane + 3] = sm.w * invk;
  }
  __syncthreads();
  // fused MLP head + log_softmax
  if (t < 128) {
    float mxA = -INFINITY, smA = 0.f;
#pragma unroll
    for (int p = 0; p < 8; ++p) {
      mxA = fmaxf(mxA, pmxA[(size_t)(g * 8 + p) * 128 + t]);
      smA += psmA[(size_t)(g * 8 + p) * 128 + t];
    }
    float mxB = -INFINITY, smB = 0.f;
#pragma unroll
    for (int p = 0; p < 4; ++p) {
      mxB = fmaxf(mxB, pmxB[(size_t)(g * 4 + p) * 128 + t]);
      smB += psmB[(size_t)(g * 4 + p) * 128 + t];
    }
    gr[t] += mxA + mxB;
    gr[t + 128] += smA * (1.f / 1024.f) + smB * (1.f / 512.f);
  }
  __syncthreads();
  if (t < 128) {
    float a = hb1[t];
    for (int kk = 0; kk < 256; ++kk) a += gr[kk] * hW1[kk * 128 + t];
    o1[t] = fmaxf(a, 0.f);
  }
  __syncthreads();
  if (t < 64) {
    float a2 = hb2[t];
    for (int kk = 0; kk < 128; ++kk) a2 += o1[kk] * hW2[kk * 64 + t];
    o2[t] = fmaxf(a2, 0.f);
  }
  __syncthreads();
  if (t < NCLS) {
    float a3 = hb3[t];
    for (int kk = 0; kk < 64; ++kk) a3 += o2[kk] * hW3[kk * NCLS + t];
    o3[t] = a3;
  }
  __syncthreads();
  if (t == 0) {
    float m = -INFINITY;
    for (int c = 0; c < NCLS; ++c) m = fmaxf(m, o3[c]);
    float sum = 0.f;
    for (int c = 0; c < NCLS; ++c) sum += expf(o3[c] - m);
    float lse = logf(sum);
    for (int c = 0; c < NCLS; ++c) out[g * NCLS + c] = o3[c] - m - lse;
  }
}

}  // namespace

extern "C" void kernel_launch(void* const* d_in, const int* in_sizes, int n_in,
                              void* d_out, int out_size, void* d_ws, size_t ws_size,
                              hipStream_t stream) {
  const float* x = (const float*)d_in[0];
  const int* ei = (const int*)d_in[1];
  const int* src = ei;
  const int* dst = ei + E_;
  const float* Wl[3]  = {(const float*)d_in[3], (const float*)d_in[7], (const float*)d_in[11]};
  const float* bl[3]  = {(const float*)d_in[4], (const float*)d_in[8], (const float*)d_in[12]};
  const float* Wpl[3] = {(const float*)d_in[5], (const float*)d_in[9], (const float*)d_in[13]};
  const float* bpl[3] = {(const float*)d_in[6], (const float*)d_in[10], (const float*)d_in[14]};
  const float* l1W = (const float*)d_in[15];
  const float* l1b = (const float*)d_in[16];
  const float* l2W = (const float*)d_in[17];
  const float* l2b = (const float*)d_in[18];
  const float* l3W = (const float*)d_in[19];
  const float* l3b = (const float*)d_in[20];

  char* p = (char*)d_ws;
  auto alloc = [&](size_t bytes) -> void* {
    void* r = (void*)p;
    p += (bytes + 255) & ~size_t(255);
    return r;
  };
  float* h      = (float*)alloc((size_t)NT * 128 * 4);
  float* t      = (float*)alloc((size_t)NT * 128 * 4);
  float* dinv   = (float*)alloc(NT * 4);
  float* ds     = (float*)alloc(NT * 4);
  float* sws    = (float*)alloc(NT * 4);
  float* scale  = (float*)alloc(NT * 4);
  float* t1     = (float*)alloc(NT * 4);
  float* raw    = (float*)alloc(NT * 4);
  float* kpmask = (float*)alloc(NT * 4);
  int*   srcp   = (int*)alloc(E_ * 4);
  int*   off    = (int*)alloc((NT + 1) * 4);
  int*   kept0  = (int*)alloc(NT * 4);
  int*   kept1  = (int*)alloc(NT * 4);
  int*   kept2  = (int*)alloc(NT * 4);
  float* pmxA   = (float*)alloc(256 * 128 * 4);
  float* psmA   = (float*)alloc(256 * 128 * 4);
  float* pmxB   = (float*)alloc(128 * 128 * 4);
  float* psmB   = (float*)alloc(128 * 128 * 4);

  int* keptL[3] = {kept0, kept1, kept2};
  const int K[3] = {1024, 512, 256};
  const int KSH[3] = {10, 9, 8};
  float* pmxL[3] = {nullptr, pmxA, pmxB};
  float* psmL[3] = {nullptr, psmA, psmB};

  const float* inF = x;
  for (int l = 0; l < 3; ++l) {
    const int* inKept = (l == 0) ? nullptr : keptL[l - 1];
    int inKsh = (l == 0) ? 11 : KSH[l - 1];
    int nrows = (l == 0) ? NT : B_ * K[l - 1];
    int mmB = nrows / 128;
    int mm_bpgsh = (l == 0) ? 4 : (l == 1 ? 3 : 2);   // 512/256/128 mm blocks
    int ag_bpgsh = (l == 0) ? 8 : (l == 1 ? 7 : 6);   // 8192/4096/2048 blocks
    int sc_bpgsh = (l == 0) ? 6 : (l == 1 ? 5 : 4);   // 2048/1024/512 blocks
    int csrB = (l == 0) ? B_ : 0;                     // csr piggybacks on mm0
    // norm of layer l-1 piggybacks on mm(l): 64 nodes/block (512 thr, 8 lanes)
    int normB = (l == 0) ? 0 : (B_ * K[l - 1]) / 64;  // 512 / 256 blocks
    int nbpgsh = (l == 1) ? 4 : 3;                    // 16 / 8 blocks per graph
    int klen = (l == 0) ? N_ : K[l - 1];
    bool last = (l == 2);
    k_matmul<<<csrB + mmB + normB, 512, 0, stream>>>(
        inF, Wl[l], t, inKept, inKsh, mm_bpgsh, mmB, scale, pmxL[l], psmL[l],
        src, dst, off, srcp, dinv, ds, sws, csrB,
        kpmask, inKept, inKsh, nbpgsh);
    k_agg<<<nrows / 8, 256, 0, stream>>>((const float4*)t, off, srcp, dinv, ds, sws,
                                         bl[l], Wpl[l], (float4*)h, t1, inKept, inKsh,
                                         ag_bpgsh);
    k_score<<<nrows / 32, 256, 0, stream>>>(t1, off, srcp, dinv, bpl[l], raw,
                                            inKept, inKsh, sc_bpgsh);
    k_pool<<<B_, 1024, 0, stream>>>(raw, dinv, ds, sws, scale, kpmask,
                                    keptL[l], (const float4*)h,
                                    1.f / (float)K[l], K[l], inKept, klen,
                                    last ? pmxA : nullptr, last ? psmA : nullptr,
                                    last ? pmxB : nullptr, last ? psmB : nullptr,
                                    l1W, l1b, l2W, l2b, l3W, l3b,
                                    last ? (float*)d_out : nullptr);
    inF = h;
  }
}